// Round 9
// baseline (262.067 us; speedup 1.0000x reference)
//
#include <hip/hip_runtime.h>

typedef unsigned int uint;
typedef unsigned short ushort;
typedef __bf16 bf16x8 __attribute__((ext_vector_type(8)));
typedef short s16x4 __attribute__((ext_vector_type(4)));
typedef float f32x4 __attribute__((ext_vector_type(4)));

__device__ __forceinline__ ushort f2bf(float f) {
  union { float f; uint u; } c; c.f = f;
  uint u = c.u + 0x7fffu + ((c.u >> 16) & 1u);
  return (ushort)(u >> 16);
}
__device__ __forceinline__ float bflo(uint u) { union { uint u; float f; } c; c.u = u << 16; return c.f; }
__device__ __forceinline__ float bfhi(uint u) { union { uint u; float f; } c; c.u = u & 0xffff0000u; return c.f; }

__device__ __forceinline__ void gload16(const void* g, void* l) {
  __builtin_amdgcn_global_load_lds((const __attribute__((address_space(1))) void*)g,
                                   (__attribute__((address_space(3))) void*)l, 16, 0, 0);
}
__device__ __forceinline__ void mfma16(f32x4& acc, s16x4 a, s16x4 b) {
  asm("v_mfma_f32_16x16x16_bf16 %0, %1, %2, %0" : "+v"(acc) : "v"(a), "v"(b));
}
__device__ __forceinline__ float fexp2(float x) {
  float y; asm("v_exp_f32 %0, %1" : "=v"(y) : "v"(x)); return y;
}

// ---------------- cast + transpose: x [B][C][4096] f32 -> xt [B][4096][C] bf16 (both tensors) ----------------
__global__ void cast_transpose(const float* __restrict__ x1, const float* __restrict__ x2,
                               ushort* __restrict__ x1t, ushort* __restrict__ x2t) {
  __shared__ float t[32][33];
  const int z = blockIdx.z, b = z & 3, tn = z >> 2;
  const float* x = tn ? x2 : x1;
  ushort* xt = tn ? x2t : x1t;
  const int pc = blockIdx.x, cc = blockIdx.y;
  const int tx = threadIdx.x, ty = threadIdx.y; // 32 x 8
  const float* xb = x + ((size_t)b * 256 + cc * 32) * 4096 + pc * 32;
#pragma unroll
  for (int i = 0; i < 4; ++i)
    t[ty * 4 + i][tx] = xb[(size_t)(ty * 4 + i) * 4096 + tx];
  __syncthreads();
  ushort* xtb = xt + ((size_t)b * 4096 + pc * 32) * 256 + cc * 32;
#pragma unroll
  for (int i = 0; i < 4; ++i)
    xtb[(size_t)(ty * 4 + i) * 256 + tx] = f2bf(t[tx][ty * 4 + i]);
}

// ---------------- all weights -> bf16, one kernel. Q weights get 1/sqrt(C)*log2(e) folded in. ----------------
__global__ void cast_weights(const float* __restrict__ w1, const float* __restrict__ w2,
                             const float* __restrict__ wqkv, const float* __restrict__ wout,
                             const float* __restrict__ wsk,
                             ushort* __restrict__ w1b, ushort* __restrict__ w2b,
                             ushort* __restrict__ wqb, ushort* __restrict__ wkvb,
                             ushort* __restrict__ woutb, ushort* __restrict__ wskb) {
  const int i = blockIdx.x * 256 + threadIdx.x;
  const float QS = 0.0625f * 1.44269504088896f;
  if (i < 65536) w1b[i] = f2bf(w1[i]);
  else if (i < 131072) w2b[i - 65536] = f2bf(w2[i - 65536]);
  else if (i < 196608) wqb[i - 131072] = f2bf(wqkv[i - 131072] * QS);
  else if (i < 327680) wkvb[i - 196608] = f2bf(wqkv[i - 131072]);
  else if (i < 393216) woutb[i - 327680] = f2bf(wout[i - 327680]);
  else wskb[i - 393216] = f2bf(wsk[i - 393216]);
}

// ---------------- GroupNorm on pixel-major bf16 [B][4096][256], G=32 (8 ch/group); z selects tensor ----------------
__global__ void groupnorm(const ushort* __restrict__ y1, ushort* __restrict__ o1,
                          const ushort* __restrict__ y2,
                          const float* __restrict__ gamma, const float* __restrict__ beta) {
  const int g = blockIdx.x, b = blockIdx.y, tn = blockIdx.z;
  const ushort* y = tn ? y2 : y1;
  ushort* gout = tn ? (ushort*)y2 : o1;
  const int tid = threadIdx.x; // 256
  const size_t base = ((size_t)b * 4096) * 256 + g * 8;
  float s = 0.f, ss = 0.f;
#pragma unroll
  for (int i = 0; i < 16; ++i) {
    int p = i * 256 + tid;
    uint4 raw = *(const uint4*)(y + base + (size_t)p * 256);
    float v0 = bflo(raw.x), v1 = bfhi(raw.x), v2 = bflo(raw.y), v3 = bfhi(raw.y);
    float v4 = bflo(raw.z), v5 = bfhi(raw.z), v6 = bflo(raw.w), v7 = bfhi(raw.w);
    s += v0 + v1 + v2 + v3 + v4 + v5 + v6 + v7;
    ss += v0 * v0 + v1 * v1 + v2 * v2 + v3 * v3 + v4 * v4 + v5 * v5 + v6 * v6 + v7 * v7;
  }
#pragma unroll
  for (int off = 1; off < 64; off <<= 1) { s += __shfl_xor(s, off); ss += __shfl_xor(ss, off); }
  __shared__ float red[10];
  if ((tid & 63) == 0) { red[tid >> 6] = s; red[4 + (tid >> 6)] = ss; }
  __syncthreads();
  if (tid == 0) {
    float S = red[0] + red[1] + red[2] + red[3];
    float SS = red[4] + red[5] + red[6] + red[7];
    float mu = S * (1.f / 32768.f);
    float var = SS * (1.f / 32768.f) - mu * mu;
    red[8] = mu; red[9] = rsqrtf(var + 1e-5f);
  }
  __syncthreads();
  const float mu = red[8], rstd = red[9];
  float ga[8], be[8];
#pragma unroll
  for (int j = 0; j < 8; ++j) { ga[j] = gamma[g * 8 + j]; be[j] = beta[g * 8 + j]; }
#pragma unroll
  for (int i = 0; i < 16; ++i) {
    int p = i * 256 + tid;
    const size_t off = base + (size_t)p * 256;
    uint4 raw = *(const uint4*)(y + off);
    float v[8] = { bflo(raw.x), bfhi(raw.x), bflo(raw.y), bfhi(raw.y),
                   bflo(raw.z), bfhi(raw.z), bflo(raw.w), bfhi(raw.w) };
    ushort o[8];
#pragma unroll
    for (int j = 0; j < 8; ++j) o[j] = f2bf((v[j] - mu) * rstd * ga[j] + be[j]);
    uint4 w;
    w.x = (uint)o[0] | ((uint)o[1] << 16); w.y = (uint)o[2] | ((uint)o[3] << 16);
    w.z = (uint)o[4] | ((uint)o[5] << 16); w.w = (uint)o[6] | ((uint)o[7] << 16);
    *(uint4*)(gout + off) = w;
  }
}

// ---------------- shared GEMM pieces: 128x128 tile, K-step 64, double-buffered LDS ----------------
__device__ __forceinline__ void g_stage(const ushort* __restrict__ A, const ushort* __restrict__ W,
                                        int m0, int n0, int ko, ushort* al, ushort* bl, int w, int l) {
#pragma unroll
  for (int j = 0; j < 4; ++j) {
    int cb = (j * 4 + w) * 64;
    int chunk = cb + l;
    int row = chunk >> 3, sl = chunk & 7;
    int col = (sl * 8) ^ ((row & 7) << 3);
    gload16(A + (size_t)(m0 + row) * 256 + ko + col, al + cb * 8);
  }
#pragma unroll
  for (int j = 0; j < 4; ++j) {
    int cb = (j * 4 + w) * 64;
    int chunk = cb + l;
    int row = chunk >> 3, sl = chunk & 7;
    int col = (sl * 8) ^ ((row & 7) << 3);
    gload16(W + (size_t)(n0 + row) * 256 + ko + col, bl + cb * 8);
  }
}

__device__ __forceinline__ void g_stage_b(const ushort* __restrict__ W,
                                          int n0, int ko, ushort* bl, int w, int l) {
#pragma unroll
  for (int j = 0; j < 4; ++j) {
    int cb = (j * 4 + w) * 64;
    int chunk = cb + l;
    int row = chunk >> 3, sl = chunk & 7;
    int col = (sl * 8) ^ ((row & 7) << 3);
    gload16(W + (size_t)(n0 + row) * 256 + ko + col, bl + cb * 8);
  }
}

__device__ __forceinline__ void g_stage_a(const ushort* __restrict__ A,
                                          int m0, int ko, ushort* al, int w, int l) {
#pragma unroll
  for (int j = 0; j < 4; ++j) {
    int cb = (j * 4 + w) * 64;
    int chunk = cb + l;
    int row = chunk >> 3, sl = chunk & 7;
    int col = (sl * 8) ^ ((row & 7) << 3);
    gload16(A + (size_t)(m0 + row) * 256 + ko + col, al + cb * 8);
  }
}

__device__ __forceinline__ void g_compute(const ushort* al, const ushort* bl,
                                          int wr, int wc, int lr, int lg, f32x4 acc[4][4]) {
#pragma unroll
  for (int kk = 0; kk < 2; ++kk) {
    bf16x8 af[4], bfr[4];
#pragma unroll
    for (int m = 0; m < 4; ++m)
      af[m] = *(const bf16x8*)&al[(wr * 64 + m * 16 + lr) * 64 + ((kk * 32 + lg * 8) ^ ((lr & 7) << 3))];
#pragma unroll
    for (int n = 0; n < 4; ++n)
      bfr[n] = *(const bf16x8*)&bl[(wc * 64 + n * 16 + lr) * 64 + ((kk * 32 + lg * 8) ^ ((lr & 7) << 3))];
#pragma unroll
    for (int m = 0; m < 4; ++m)
#pragma unroll
      for (int n = 0; n < 4; ++n)
        acc[m][n] = __builtin_amdgcn_mfma_f32_16x16x32_bf16(af[m], bfr[n], acc[m][n], 0, 0, 0);
  }
}

// ---------------- conv1 + conv2 fused: z = t*4 + b ----------------
__launch_bounds__(256)
__global__ void conv_pair(const ushort* __restrict__ x1t, const ushort* __restrict__ x2t,
                          const ushort* __restrict__ w1b, const ushort* __restrict__ w2b,
                          const float* __restrict__ b1, const float* __restrict__ b2,
                          ushort* __restrict__ y1t, ushort* __restrict__ y2t) {
  __shared__ ushort al[2][8192];
  __shared__ ushort bl[2][8192];
  const int z = blockIdx.z, b = z & 3, t = z >> 2;
  const ushort* A = (t ? x2t : x1t) + (size_t)b * 4096 * 256;
  const ushort* W = t ? w2b : w1b;
  const float* bias = t ? b2 : b1;
  ushort* out = t ? y2t : y1t;
  const int m0 = blockIdx.y * 128, n0 = blockIdx.x * 128;
  const int tid = threadIdx.x, w = tid >> 6, l = tid & 63;
  const int wr = w >> 1, wc = w & 1, lr = l & 15, lg = l >> 4;
  f32x4 acc[4][4] = {};
  g_stage(A, W, m0, n0, 0, al[0], bl[0], w, l);
  __syncthreads();
  for (int s = 0; s < 4; ++s) {
    int cur = s & 1;
    if (s + 1 < 4) g_stage(A, W, m0, n0, (s + 1) * 64, al[cur ^ 1], bl[cur ^ 1], w, l);
    g_compute(al[cur], bl[cur], wr, wc, lr, lg, acc);
    __syncthreads();
  }
#pragma unroll
  for (int n = 0; n < 4; ++n) {
    int o = n0 + wc * 64 + n * 16 + lr;
    float bv = bias[o];
#pragma unroll
    for (int m = 0; m < 4; ++m) {
      int p0 = m0 + wr * 64 + m * 16 + lg * 4;
#pragma unroll
      for (int r = 0; r < 4; ++r)
        out[((size_t)b * 4096 + p0 + r) * 256 + o] = f2bf(acc[m][n][r] + bv);
    }
  }
}

// ---------------- q-proj + kv-proj fused: x<2 -> q1 (from g1t), x>=2 -> [k2|v2] (from y2t) ----------------
__launch_bounds__(256)
__global__ void gemm_qkv(const ushort* __restrict__ g1t, const ushort* __restrict__ y2t,
                         const ushort* __restrict__ wqb, const ushort* __restrict__ wkvb,
                         ushort* __restrict__ q1t, ushort* __restrict__ k2t, ushort* __restrict__ v2) {
  __shared__ ushort al[2][8192];
  __shared__ ushort bl[2][8192];
  const int b = blockIdx.z, x = blockIdx.x;
  const bool isq = x < 2;
  const ushort* A = (isq ? g1t : y2t) + (size_t)b * 4096 * 256;
  const ushort* W = isq ? wqb : wkvb;
  const int n0 = isq ? x * 128 : (x - 2) * 128;
  const int m0 = blockIdx.y * 128;
  const int tid = threadIdx.x, w = tid >> 6, l = tid & 63;
  const int wr = w >> 1, wc = w & 1, lr = l & 15, lg = l >> 4;
  f32x4 acc[4][4] = {};
  g_stage(A, W, m0, n0, 0, al[0], bl[0], w, l);
  __syncthreads();
  for (int s = 0; s < 4; ++s) {
    int cur = s & 1;
    if (s + 1 < 4) g_stage(A, W, m0, n0, (s + 1) * 64, al[cur ^ 1], bl[cur ^ 1], w, l);
    g_compute(al[cur], bl[cur], wr, wc, lr, lg, acc);
    __syncthreads();
  }
#pragma unroll
  for (int n = 0; n < 4; ++n) {
    int o = n0 + wc * 64 + n * 16 + lr;
#pragma unroll
    for (int m = 0; m < 4; ++m) {
      int p0 = m0 + wr * 64 + m * 16 + lg * 4;
#pragma unroll
      for (int r = 0; r < 4; ++r) {
        float val = acc[m][n][r];
        int p = p0 + r;
        if (isq) q1t[((size_t)b * 4096 + p) * 256 + o] = f2bf(val);
        else if (o < 256) k2t[((size_t)b * 4096 + p) * 256 + o] = f2bf(val);
        else v2[((size_t)b * 256 + (o - 256)) * 4096 + p] = f2bf(val);
      }
    }
  }
}

// ---------------- final: out = merge(op0,op1)@wout^T + bout + y1@wsk^T + bsk, f32 channel-major -------------
__launch_bounds__(256)
__global__ void gemm_final(const ushort* __restrict__ op0, const ushort* __restrict__ op1,
                           const float* __restrict__ ml, const ushort* __restrict__ y1t,
                           const ushort* __restrict__ woutb, const ushort* __restrict__ wskb,
                           const float* __restrict__ bout, const float* __restrict__ bsk,
                           float* __restrict__ out) {
  __shared__ ushort smem[32768];
  ushort* al0 = smem;            ushort* al1 = smem + 8192;
  ushort* bl0 = smem + 16384;    ushort* bl1 = smem + 24576;
  const int b = blockIdx.z;
  const int m0 = blockIdx.y * 128, n0 = blockIdx.x * 128;
  const int tid = threadIdx.x, w = tid >> 6, l = tid & 63;
  const int wr = w >> 1, wc = w & 1, lr = l & 15, lg = l >> 4;
  const float2* ml2 = (const float2*)ml;
  const ushort* A1 = y1t + (size_t)b * 4096 * 256;

  int rowj[4], colj[4], ldsj[4];
  float w0j[4], w1j[4];
#pragma unroll
  for (int j = 0; j < 4; ++j) {
    int chunk = (j * 4 + w) * 64 + l;
    int row = chunk >> 3, sl = chunk & 7;
    rowj[j] = row; colj[j] = sl * 8;
    ldsj[j] = row * 64 + ((sl * 8) ^ ((row & 7) << 3));
    float2 a = ml2[(size_t)b * 4096 + m0 + row];
    float2 c = ml2[(size_t)(4 + b) * 4096 + m0 + row];
    float m = fmaxf(a.x, c.x);
    float e0 = fexp2(a.x - m), e1 = fexp2(c.x - m);
    float inv = 1.f / (a.y * e0 + c.y * e1);
    w0j[j] = e0 * inv; w1j[j] = e1 * inv;
  }

  auto stageA_merge = [&](int ko, ushort* al) {
    uint4 r0[4], r1[4];
#pragma unroll
    for (int j = 0; j < 4; ++j) {
      size_t off = ((size_t)b * 4096 + m0 + rowj[j]) * 256 + ko + colj[j];
      r0[j] = *(const uint4*)(op0 + off);
      r1[j] = *(const uint4*)(op1 + off);
    }
#pragma unroll
    for (int j = 0; j < 4; ++j) {
      uint rr[4] = { r0[j].x, r0[j].y, r0[j].z, r0[j].w };
      uint ss[4] = { r1[j].x, r1[j].y, r1[j].z, r1[j].w };
      ushort o[8];
#pragma unroll
      for (int q = 0; q < 4; ++q) {
        o[q * 2]     = f2bf(bflo(rr[q]) * w0j[j] + bflo(ss[q]) * w1j[j]);
        o[q * 2 + 1] = f2bf(bfhi(rr[q]) * w0j[j] + bfhi(ss[q]) * w1j[j]);
      }
      uint4 wv;
      wv.x = (uint)o[0] | ((uint)o[1] << 16); wv.y = (uint)o[2] | ((uint)o[3] << 16);
      wv.z = (uint)o[4] | ((uint)o[5] << 16); wv.w = (uint)o[6] | ((uint)o[7] << 16);
      *(uint4*)&al[ldsj[j]] = wv;
    }
  };

  f32x4 acc[4][4] = {};
  stageA_merge(0, al0);
  g_stage_b(woutb, n0, 0, bl0, w, l);
  __syncthreads();
  for (int s = 0; s < 8; ++s) {
    int cur = s & 1;
    if (s + 1 < 8) {
      int ko = ((s + 1) & 3) * 64;
      ushort* an = cur ? al0 : al1;
      ushort* bn = cur ? bl0 : bl1;
      if (s + 1 < 4) stageA_merge(ko, an);
      else g_stage_a(A1, m0, ko, an, w, l);
      g_stage_b((s + 1 >= 4) ? wskb : woutb, n0, ko, bn, w, l);
    }
    g_compute(cur ? al1 : al0, cur ? bl1 : bl0, wr, wc, lr, lg, acc);
    __syncthreads();
  }
  float4* cl = (float4*)smem; // [128 o][32 f4]
#pragma unroll
  for (int n = 0; n < 4; ++n) {
    int o = wc * 64 + n * 16 + lr;
    float bv = bout[n0 + o] + bsk[n0 + o];
#pragma unroll
    for (int m = 0; m < 4; ++m) {
      int pf4 = wr * 16 + m * 4 + lg;
      f32x4 v = acc[m][n];
      float4 vv; vv.x = v[0] + bv; vv.y = v[1] + bv; vv.z = v[2] + bv; vv.w = v[3] + bv;
      cl[o * 32 + (pf4 ^ (o & 31))] = vv;
    }
  }
  __syncthreads();
  float4* og = (float4*)(out + ((size_t)b * 256 + n0) * 4096 + m0);
#pragma unroll
  for (int i = 0; i < 16; ++i) {
    int o = i * 8 + (tid >> 5);
    int f4 = tid & 31;
    og[(size_t)o * 1024 + f4] = cl[o * 32 + (f4 ^ (o & 31))];
  }
}

// ---------------- flash attention, k-split 2-way, q-width 32/wave: QBLK=128, KVBLK=32 ----------------
// LDS-bytes-bound fix: each wave handles TWO 16-q fragment sets (A: rows w*32+lr, B: +16). Every K ds_read
// feeds 2 MFMAs and every V fragment feeds 2 PV MFMAs -> LDS traffic per unit work HALVES (4.2 GB -> 2.1 GB
// total; ~64 us data-path floor). Grid 256 (1 block/CU, 4 waves); VGPR ~240 -> launch_bounds(256,1).
// K swizzle REVERTED to (row&15)<<4 (measured best; b128 column reads are structurally ~2x, see r8 PM).
__launch_bounds__(256, 1)
__global__ void attn(const ushort* __restrict__ Q, const ushort* __restrict__ K,
                     const ushort* __restrict__ V, ushort* __restrict__ op0,
                     ushort* __restrict__ op1, float* __restrict__ ml) {
  __shared__ ushort kb[3][32 * 256];  // 48 KB
  __shared__ ushort vb[2][256 * 32];  // 32 KB
  const int bid = blockIdx.x;
  const int xcd = bid & 7, r = bid >> 3;
  const int b = xcd >> 1;
  const int kh = r & 1;
  const int qt = (xcd & 1) * 16 + (r >> 1);   // 128-row q tile index, 0..31
  const int tid = threadIdx.x;
  const int w = tid >> 6, l = tid & 63;
  const int lr = l & 15, lg = l >> 4;

  const ushort* Qb = Q + (size_t)b * 4096 * 256;
  const ushort* Kb = K + (size_t)b * 4096 * 256 + (size_t)kh * 2048 * 256;
  const ushort* Vb = V + (size_t)b * 256 * 4096 + kh * 2048;

  int kOff[4], vOff[4];
#pragma unroll
  for (int j = 0; j < 4; ++j) {
    int c = (j * 4 + w) * 64 + l;
    int krow = c >> 5, ksl = c & 31;
    kOff[j] = krow * 256 + ((ksl * 8) ^ ((krow & 15) << 4));
    int R = c >> 2, CH = c & 3;
    int vd = R ^ ((R >> 1) & 1);
    int gch = CH ^ ((R >> 1) & 3);
    vOff[j] = vd * 4096 + gch * 8;
  }
  auto stageK = [&](int kt, ushort* dst) {
#pragma unroll
    for (int j = 0; j < 4; ++j)
      gload16(Kb + (size_t)kt * 8192 + kOff[j], dst + (j * 4 + w) * 512);
  };
  auto stageV = [&](int kt, ushort* dst) {
#pragma unroll
    for (int j = 0; j < 4; ++j)
      gload16(Vb + (size_t)kt * 32 + vOff[j], dst + (j * 4 + w) * 512);
  };

  // two Q fragment sets straight to registers
  bf16x8 qfA[8], qfB[8];
  {
    const ushort* qa = Qb + (size_t)(qt * 128 + w * 32 + lr) * 256 + lg * 8;
    const ushort* qc = qa + 16 * 256;
#pragma unroll
    for (int kk = 0; kk < 8; ++kk) {
      qfA[kk] = *(const bf16x8*)(qa + kk * 32);
      qfB[kk] = *(const bf16x8*)(qc + kk * 32);
    }
  }

  stageK(0, kb[0]);
  stageV(0, vb[0]);
  stageK(1, kb[1]);
  asm volatile("s_waitcnt vmcnt(4)" ::: "memory");
  __builtin_amdgcn_s_barrier();

  const int lrp = lr ^ ((lr >> 1) & 1);
  const int vsw = (lr >> 1) & 3;
  const int vbase0 = lrp * 32 + (((lg >> 1)) ^ vsw) * 8 + (lg & 1) * 4;
  const int vbase1 = lrp * 32 + ((2 + (lg >> 1)) ^ vsw) * 8 + (lg & 1) * 4;

  float mA = -1e30f, lsA = 0.f, mB = -1e30f, lsB = 0.f;
  f32x4 oaccA[16] = {}, oaccB[16] = {};
  int kc = 0, kn2 = 2;

  for (int kt = 0; kt < 64; ++kt) {
    const ushort* kl = kb[kc];
    const ushort* vl = vb[kt & 1];

    // S^T for both q-sets: each kv read feeds 2 MFMAs
    __builtin_amdgcn_s_setprio(1);
    f32x4 sA[2] = {}, sB[2] = {};
#pragma unroll
    for (int kk = 0; kk < 8; ++kk) {
#pragma unroll
      for (int n = 0; n < 2; ++n) {
        bf16x8 kv = *(const bf16x8*)&kl[(n * 16 + lr) * 256 + ((kk * 32 + lg * 8) ^ (lr << 4))];
        sA[n] = __builtin_amdgcn_mfma_f32_16x16x32_bf16(kv, qfA[kk], sA[n], 0, 0, 0);
        sB[n] = __builtin_amdgcn_mfma_f32_16x16x32_bf16(kv, qfB[kk], sB[n], 0, 0, 0);
      }
    }
    __builtin_amdgcn_s_setprio(0);

    if (kt + 1 < 64) stageV(kt + 1, vb[(kt + 1) & 1]);
    if (kt + 2 < 64) stageK(kt + 2, kb[kn2]);

    float tmA = fmaxf(fmaxf(fmaxf(sA[0][0], sA[0][1]), fmaxf(sA[0][2], sA[0][3])),
                      fmaxf(fmaxf(sA[1][0], sA[1][1]), fmaxf(sA[1][2], sA[1][3])));
    tmA = fmaxf(tmA, __shfl_xor(tmA, 16));
    tmA = fmaxf(tmA, __shfl_xor(tmA, 32));
    float tmB = fmaxf(fmaxf(fmaxf(sB[0][0], sB[0][1]), fmaxf(sB[0][2], sB[0][3])),
                      fmaxf(fmaxf(sB[1][0], sB[1][1]), fmaxf(sB[1][2], sB[1][3])));
    tmB = fmaxf(tmB, __shfl_xor(tmB, 16));
    tmB = fmaxf(tmB, __shfl_xor(tmB, 32));

    if (__any((tmA > mA + 11.5f) || (tmB > mB + 11.5f))) { // defer-max
      {
        float mn = fmaxf(mA, tmA);
        float al = fexp2(mA - mn);
        mA = mn; lsA *= al;
        float ar[4];
#pragma unroll
        for (int r2 = 0; r2 < 4; ++r2) ar[r2] = __shfl(al, lg * 4 + r2);
#pragma unroll
        for (int nf = 0; nf < 16; ++nf)
#pragma unroll
          for (int r2 = 0; r2 < 4; ++r2) oaccA[nf][r2] *= ar[r2];
      }
      {
        float mn = fmaxf(mB, tmB);
        float al = fexp2(mB - mn);
        mB = mn; lsB *= al;
        float ar[4];
#pragma unroll
        for (int r2 = 0; r2 < 4; ++r2) ar[r2] = __shfl(al, lg * 4 + r2);
#pragma unroll
        for (int nf = 0; nf < 16; ++nf)
#pragma unroll
          for (int r2 = 0; r2 < 4; ++r2) oaccB[nf][r2] *= ar[r2];
      }
    }

    uint pwA[2][2], pwB[2][2];
#pragma unroll
    for (int n = 0; n < 2; ++n) {
      float a0 = fexp2(sA[n][0] - mA), a1 = fexp2(sA[n][1] - mA);
      float a2 = fexp2(sA[n][2] - mA), a3 = fexp2(sA[n][3] - mA);
      lsA += (a0 + a1) + (a2 + a3);
      asm("v_cvt_pk_bf16_f32 %0, %1, %2" : "=v"(pwA[n][0]) : "v"(a0), "v"(a1));
      asm("v_cvt_pk_bf16_f32 %0, %1, %2" : "=v"(pwA[n][1]) : "v"(a2), "v"(a3));
      float b0 = fexp2(sB[n][0] - mB), b1 = fexp2(sB[n][1] - mB);
      float b2 = fexp2(sB[n][2] - mB), b3 = fexp2(sB[n][3] - mB);
      lsB += (b0 + b1) + (b2 + b3);
      asm("v_cvt_pk_bf16_f32 %0, %1, %2" : "=v"(pwB[n][0]) : "v"(b0), "v"(b1));
      asm("v_cvt_pk_bf16_f32 %0, %1, %2" : "=v"(pwB[n][1]) : "v"(b2), "v"(b3));
    }

    // O += P * V : each V fragment feeds both q-sets
    __builtin_amdgcn_s_setprio(1);
#pragma unroll
    for (int n = 0; n < 2; ++n) {
      uint2 ua; ua.x = pwA[n][0]; ua.y = pwA[n][1];
      s16x4 paA = __builtin_bit_cast(s16x4, ua);
      uint2 ub; ub.x = pwB[n][0]; ub.y = pwB[n][1];
      s16x4 paB = __builtin_bit_cast(s16x4, ub);
      const int vbase = n ? vbase1 : vbase0;
#pragma unroll
      for (int nf = 0; nf < 16; ++nf) {
        s16x4 vv = *(const s16x4*)&vl[nf * 512 + vbase];
        mfma16(oaccA[nf], paA, vv);
        mfma16(oaccB[nf], paB, vv);
      }
    }
    __builtin_amdgcn_s_setprio(0);

    if (kt < 63) {
      if (kt < 62) asm volatile("s_waitcnt vmcnt(4)" ::: "memory");
      else         asm volatile("s_waitcnt vmcnt(0)" ::: "memory");
      __builtin_amdgcn_s_barrier();
    }
    kc = (kc == 2) ? 0 : kc + 1;
    kn2 = (kn2 == 2) ? 0 : kn2 + 1;
  }

  float ra = lsA;
  ra += __shfl_xor(ra, 16);
  ra += __shfl_xor(ra, 32);
  float rb = lsB;
  rb += __shfl_xor(rb, 16);
  rb += __shfl_xor(rb, 32);

  if (lg == 0) {
    float2* ml2 = (float2*)ml;
    int qp = qt * 128 + w * 32 + lr;
    float2 va; va.x = mA; va.y = ra;
    ml2[((size_t)(kh * 4 + b)) * 4096 + qp] = va;
    float2 vc; vc.x = mB; vc.y = rb;
    ml2[((size_t)(kh * 4 + b)) * 4096 + qp + 16] = vc;
  }

  ushort* Ob = (kh ? op1 : op0) + (size_t)b * 4096 * 256;
#pragma unroll
  for (int nf = 0; nf < 16; ++nf) {
#pragma unroll
    for (int r2 = 0; r2 < 4; ++r2) {
      int qp = qt * 128 + w * 32 + lg * 4 + r2;
      Ob[(size_t)qp * 256 + nf * 16 + lr] = f2bf(oaccA[nf][r2]);
      Ob[(size_t)(qp + 16) * 256 + nf * 16 + lr] = f2bf(oaccB[nf][r2]);
    }
  }
}

extern "C" void kernel_launch(void* const* d_in, const int* in_sizes, int n_in,
                              void* d_out, int out_size, void* d_ws, size_t ws_size,
                              hipStream_t stream) {
  const float* x1 = (const float*)d_in[0];
  const float* x2 = (const float*)d_in[1];
  const float* w1 = (const float*)d_in[2];
  const float* b1 = (const float*)d_in[3];
  const float* w2 = (const float*)d_in[4];
  const float* b2 = (const float*)d_in[5];
  const float* gn_w = (const float*)d_in[6];
  const float* gn_b = (const float*)d_in[7];
  const float* wqkv = (const float*)d_in[8];
  const float* wout = (const float*)d_in[9];
  const float* bout = (const float*)d_in[10];
  const float* wsk = (const float*)d_in[11];
  const float* bsk = (const float*)d_in[12];
  float* out = (float*)d_out;

  const size_t NB = (size_t)4 * 4096 * 256;
  ushort* x1t = (ushort*)d_ws;      // later reused as q1t
  ushort* x2t = x1t + NB;           // later reused as k2t
  ushort* y1t = x2t + NB;           // persists (skip input)
  ushort* y2t = y1t + NB;           // GN'd in place -> g2t; later reused as O-partial kh=0
  ushort* g1t = y2t + NB;           // later reused as O-partial kh=1
  ushort* v2  = g1t + NB;
  ushort* w1b = v2 + NB;
  ushort* w2b = w1b + 65536;
  ushort* wqb = w2b + 65536;
  ushort* wkvb = wqb + 65536;       // 131072
  ushort* woutb = wkvb + 131072;
  ushort* wskb = woutb + 65536;
  float* mlbuf = (float*)(wskb + 65536); // 2*4*4096 float2

  cast_transpose<<<dim3(128, 8, 8), dim3(32, 8), 0, stream>>>(x1, x2, x1t, x2t);
  cast_weights<<<1792, 256, 0, stream>>>(w1, w2, wqkv, wout, wsk,
                                         w1b, w2b, wqb, wkvb, woutb, wskb);
  conv_pair<<<dim3(2, 32, 8), 256, 0, stream>>>(x1t, x2t, w1b, w2b, b1, b2, y1t, y2t);
  groupnorm<<<dim3(32, 4, 2), 256, 0, stream>>>(y1t, g1t, y2t, gn_w, gn_b);
  gemm_qkv<<<dim3(6, 32, 4), 256, 0, stream>>>(g1t, y2t, wqb, wkvb, x1t, x2t, v2);
  attn<<<256, 256, 0, stream>>>(x1t, x2t, v2, y2t, g1t, mlbuf);
  gemm_final<<<dim3(2, 32, 4), 256, 0, stream>>>(y2t, g1t, mlbuf, y1t, woutb, wskb, bout, bsk, out);
}

// Round 10
// 230.556 us; speedup vs baseline: 1.1367x; 1.1367x over previous
//
#include <hip/hip_runtime.h>

typedef unsigned int uint;
typedef unsigned short ushort;
typedef __bf16 bf16x8 __attribute__((ext_vector_type(8)));
typedef short s16x4 __attribute__((ext_vector_type(4)));
typedef float f32x4 __attribute__((ext_vector_type(4)));

__device__ __forceinline__ ushort f2bf(float f) {
  union { float f; uint u; } c; c.f = f;
  uint u = c.u + 0x7fffu + ((c.u >> 16) & 1u);
  return (ushort)(u >> 16);
}
__device__ __forceinline__ float bflo(uint u) { union { uint u; float f; } c; c.u = u << 16; return c.f; }
__device__ __forceinline__ float bfhi(uint u) { union { uint u; float f; } c; c.u = u & 0xffff0000u; return c.f; }

__device__ __forceinline__ void gload16(const void* g, void* l) {
  __builtin_amdgcn_global_load_lds((const __attribute__((address_space(1))) void*)g,
                                   (__attribute__((address_space(3))) void*)l, 16, 0, 0);
}
__device__ __forceinline__ void mfma16(f32x4& acc, s16x4 a, s16x4 b) {
  asm("v_mfma_f32_16x16x16_bf16 %0, %1, %2, %0" : "+v"(acc) : "v"(a), "v"(b));
}
__device__ __forceinline__ float fexp2(float x) {
  float y; asm("v_exp_f32 %0, %1" : "=v"(y) : "v"(x)); return y;
}

// ---------------- cast + transpose: x [B][C][4096] f32 -> xt [B][4096][C] bf16 (both tensors) ----------------
__global__ void cast_transpose(const float* __restrict__ x1, const float* __restrict__ x2,
                               ushort* __restrict__ x1t, ushort* __restrict__ x2t) {
  __shared__ float t[32][33];
  const int z = blockIdx.z, b = z & 3, tn = z >> 2;
  const float* x = tn ? x2 : x1;
  ushort* xt = tn ? x2t : x1t;
  const int pc = blockIdx.x, cc = blockIdx.y;
  const int tx = threadIdx.x, ty = threadIdx.y; // 32 x 8
  const float* xb = x + ((size_t)b * 256 + cc * 32) * 4096 + pc * 32;
#pragma unroll
  for (int i = 0; i < 4; ++i)
    t[ty * 4 + i][tx] = xb[(size_t)(ty * 4 + i) * 4096 + tx];
  __syncthreads();
  ushort* xtb = xt + ((size_t)b * 4096 + pc * 32) * 256 + cc * 32;
#pragma unroll
  for (int i = 0; i < 4; ++i)
    xtb[(size_t)(ty * 4 + i) * 256 + tx] = f2bf(t[tx][ty * 4 + i]);
}

// ---------------- all weights -> bf16, one kernel. Q weights get 1/sqrt(C)*log2(e) folded in. ----------------
__global__ void cast_weights(const float* __restrict__ w1, const float* __restrict__ w2,
                             const float* __restrict__ wqkv, const float* __restrict__ wout,
                             const float* __restrict__ wsk,
                             ushort* __restrict__ w1b, ushort* __restrict__ w2b,
                             ushort* __restrict__ wqb, ushort* __restrict__ wkvb,
                             ushort* __restrict__ woutb, ushort* __restrict__ wskb) {
  const int i = blockIdx.x * 256 + threadIdx.x;
  const float QS = 0.0625f * 1.44269504088896f;
  if (i < 65536) w1b[i] = f2bf(w1[i]);
  else if (i < 131072) w2b[i - 65536] = f2bf(w2[i - 65536]);
  else if (i < 196608) wqb[i - 131072] = f2bf(wqkv[i - 131072] * QS);
  else if (i < 327680) wkvb[i - 196608] = f2bf(wqkv[i - 131072]);
  else if (i < 393216) woutb[i - 327680] = f2bf(wout[i - 327680]);
  else wskb[i - 393216] = f2bf(wsk[i - 393216]);
}

// ---------------- GroupNorm on pixel-major bf16 [B][4096][256], G=32 (8 ch/group); z selects tensor ----------------
__global__ void groupnorm(const ushort* __restrict__ y1, ushort* __restrict__ o1,
                          const ushort* __restrict__ y2,
                          const float* __restrict__ gamma, const float* __restrict__ beta) {
  const int g = blockIdx.x, b = blockIdx.y, tn = blockIdx.z;
  const ushort* y = tn ? y2 : y1;
  ushort* gout = tn ? (ushort*)y2 : o1;
  const int tid = threadIdx.x; // 256
  const size_t base = ((size_t)b * 4096) * 256 + g * 8;
  float s = 0.f, ss = 0.f;
#pragma unroll
  for (int i = 0; i < 16; ++i) {
    int p = i * 256 + tid;
    uint4 raw = *(const uint4*)(y + base + (size_t)p * 256);
    float v0 = bflo(raw.x), v1 = bfhi(raw.x), v2 = bflo(raw.y), v3 = bfhi(raw.y);
    float v4 = bflo(raw.z), v5 = bfhi(raw.z), v6 = bflo(raw.w), v7 = bfhi(raw.w);
    s += v0 + v1 + v2 + v3 + v4 + v5 + v6 + v7;
    ss += v0 * v0 + v1 * v1 + v2 * v2 + v3 * v3 + v4 * v4 + v5 * v5 + v6 * v6 + v7 * v7;
  }
#pragma unroll
  for (int off = 1; off < 64; off <<= 1) { s += __shfl_xor(s, off); ss += __shfl_xor(ss, off); }
  __shared__ float red[10];
  if ((tid & 63) == 0) { red[tid >> 6] = s; red[4 + (tid >> 6)] = ss; }
  __syncthreads();
  if (tid == 0) {
    float S = red[0] + red[1] + red[2] + red[3];
    float SS = red[4] + red[5] + red[6] + red[7];
    float mu = S * (1.f / 32768.f);
    float var = SS * (1.f / 32768.f) - mu * mu;
    red[8] = mu; red[9] = rsqrtf(var + 1e-5f);
  }
  __syncthreads();
  const float mu = red[8], rstd = red[9];
  float ga[8], be[8];
#pragma unroll
  for (int j = 0; j < 8; ++j) { ga[j] = gamma[g * 8 + j]; be[j] = beta[g * 8 + j]; }
#pragma unroll
  for (int i = 0; i < 16; ++i) {
    int p = i * 256 + tid;
    const size_t off = base + (size_t)p * 256;
    uint4 raw = *(const uint4*)(y + off);
    float v[8] = { bflo(raw.x), bfhi(raw.x), bflo(raw.y), bfhi(raw.y),
                   bflo(raw.z), bfhi(raw.z), bflo(raw.w), bfhi(raw.w) };
    ushort o[8];
#pragma unroll
    for (int j = 0; j < 8; ++j) o[j] = f2bf((v[j] - mu) * rstd * ga[j] + be[j]);
    uint4 w;
    w.x = (uint)o[0] | ((uint)o[1] << 16); w.y = (uint)o[2] | ((uint)o[3] << 16);
    w.z = (uint)o[4] | ((uint)o[5] << 16); w.w = (uint)o[6] | ((uint)o[7] << 16);
    *(uint4*)(gout + off) = w;
  }
}

// ---------------- shared GEMM pieces: 128x128 tile, K-step 64, double-buffered LDS ----------------
__device__ __forceinline__ void g_stage(const ushort* __restrict__ A, const ushort* __restrict__ W,
                                        int m0, int n0, int ko, ushort* al, ushort* bl, int w, int l) {
#pragma unroll
  for (int j = 0; j < 4; ++j) {
    int cb = (j * 4 + w) * 64;
    int chunk = cb + l;
    int row = chunk >> 3, sl = chunk & 7;
    int col = (sl * 8) ^ ((row & 7) << 3);
    gload16(A + (size_t)(m0 + row) * 256 + ko + col, al + cb * 8);
  }
#pragma unroll
  for (int j = 0; j < 4; ++j) {
    int cb = (j * 4 + w) * 64;
    int chunk = cb + l;
    int row = chunk >> 3, sl = chunk & 7;
    int col = (sl * 8) ^ ((row & 7) << 3);
    gload16(W + (size_t)(n0 + row) * 256 + ko + col, bl + cb * 8);
  }
}

__device__ __forceinline__ void g_stage_b(const ushort* __restrict__ W,
                                          int n0, int ko, ushort* bl, int w, int l) {
#pragma unroll
  for (int j = 0; j < 4; ++j) {
    int cb = (j * 4 + w) * 64;
    int chunk = cb + l;
    int row = chunk >> 3, sl = chunk & 7;
    int col = (sl * 8) ^ ((row & 7) << 3);
    gload16(W + (size_t)(n0 + row) * 256 + ko + col, bl + cb * 8);
  }
}

__device__ __forceinline__ void g_stage_a(const ushort* __restrict__ A,
                                          int m0, int ko, ushort* al, int w, int l) {
#pragma unroll
  for (int j = 0; j < 4; ++j) {
    int cb = (j * 4 + w) * 64;
    int chunk = cb + l;
    int row = chunk >> 3, sl = chunk & 7;
    int col = (sl * 8) ^ ((row & 7) << 3);
    gload16(A + (size_t)(m0 + row) * 256 + ko + col, al + cb * 8);
  }
}

__device__ __forceinline__ void g_compute(const ushort* al, const ushort* bl,
                                          int wr, int wc, int lr, int lg, f32x4 acc[4][4]) {
#pragma unroll
  for (int kk = 0; kk < 2; ++kk) {
    bf16x8 af[4], bfr[4];
#pragma unroll
    for (int m = 0; m < 4; ++m)
      af[m] = *(const bf16x8*)&al[(wr * 64 + m * 16 + lr) * 64 + ((kk * 32 + lg * 8) ^ ((lr & 7) << 3))];
#pragma unroll
    for (int n = 0; n < 4; ++n)
      bfr[n] = *(const bf16x8*)&bl[(wc * 64 + n * 16 + lr) * 64 + ((kk * 32 + lg * 8) ^ ((lr & 7) << 3))];
#pragma unroll
    for (int m = 0; m < 4; ++m)
#pragma unroll
      for (int n = 0; n < 4; ++n)
        acc[m][n] = __builtin_amdgcn_mfma_f32_16x16x32_bf16(af[m], bfr[n], acc[m][n], 0, 0, 0);
  }
}

// ---------------- conv1 + conv2 fused: z = t*4 + b ----------------
__launch_bounds__(256)
__global__ void conv_pair(const ushort* __restrict__ x1t, const ushort* __restrict__ x2t,
                          const ushort* __restrict__ w1b, const ushort* __restrict__ w2b,
                          const float* __restrict__ b1, const float* __restrict__ b2,
                          ushort* __restrict__ y1t, ushort* __restrict__ y2t) {
  __shared__ ushort al[2][8192];
  __shared__ ushort bl[2][8192];
  const int z = blockIdx.z, b = z & 3, t = z >> 2;
  const ushort* A = (t ? x2t : x1t) + (size_t)b * 4096 * 256;
  const ushort* W = t ? w2b : w1b;
  const float* bias = t ? b2 : b1;
  ushort* out = t ? y2t : y1t;
  const int m0 = blockIdx.y * 128, n0 = blockIdx.x * 128;
  const int tid = threadIdx.x, w = tid >> 6, l = tid & 63;
  const int wr = w >> 1, wc = w & 1, lr = l & 15, lg = l >> 4;
  f32x4 acc[4][4] = {};
  g_stage(A, W, m0, n0, 0, al[0], bl[0], w, l);
  __syncthreads();
  for (int s = 0; s < 4; ++s) {
    int cur = s & 1;
    if (s + 1 < 4) g_stage(A, W, m0, n0, (s + 1) * 64, al[cur ^ 1], bl[cur ^ 1], w, l);
    g_compute(al[cur], bl[cur], wr, wc, lr, lg, acc);
    __syncthreads();
  }
#pragma unroll
  for (int n = 0; n < 4; ++n) {
    int o = n0 + wc * 64 + n * 16 + lr;
    float bv = bias[o];
#pragma unroll
    for (int m = 0; m < 4; ++m) {
      int p0 = m0 + wr * 64 + m * 16 + lg * 4;
#pragma unroll
      for (int r = 0; r < 4; ++r)
        out[((size_t)b * 4096 + p0 + r) * 256 + o] = f2bf(acc[m][n][r] + bv);
    }
  }
}

// ---------------- q-proj + kv-proj fused: x<2 -> q1 (from g1t), x>=2 -> [k2|v2] (from y2t) ----------------
__launch_bounds__(256)
__global__ void gemm_qkv(const ushort* __restrict__ g1t, const ushort* __restrict__ y2t,
                         const ushort* __restrict__ wqb, const ushort* __restrict__ wkvb,
                         ushort* __restrict__ q1t, ushort* __restrict__ k2t, ushort* __restrict__ v2) {
  __shared__ ushort al[2][8192];
  __shared__ ushort bl[2][8192];
  const int b = blockIdx.z, x = blockIdx.x;
  const bool isq = x < 2;
  const ushort* A = (isq ? g1t : y2t) + (size_t)b * 4096 * 256;
  const ushort* W = isq ? wqb : wkvb;
  const int n0 = isq ? x * 128 : (x - 2) * 128;
  const int m0 = blockIdx.y * 128;
  const int tid = threadIdx.x, w = tid >> 6, l = tid & 63;
  const int wr = w >> 1, wc = w & 1, lr = l & 15, lg = l >> 4;
  f32x4 acc[4][4] = {};
  g_stage(A, W, m0, n0, 0, al[0], bl[0], w, l);
  __syncthreads();
  for (int s = 0; s < 4; ++s) {
    int cur = s & 1;
    if (s + 1 < 4) g_stage(A, W, m0, n0, (s + 1) * 64, al[cur ^ 1], bl[cur ^ 1], w, l);
    g_compute(al[cur], bl[cur], wr, wc, lr, lg, acc);
    __syncthreads();
  }
#pragma unroll
  for (int n = 0; n < 4; ++n) {
    int o = n0 + wc * 64 + n * 16 + lr;
#pragma unroll
    for (int m = 0; m < 4; ++m) {
      int p0 = m0 + wr * 64 + m * 16 + lg * 4;
#pragma unroll
      for (int r = 0; r < 4; ++r) {
        float val = acc[m][n][r];
        int p = p0 + r;
        if (isq) q1t[((size_t)b * 4096 + p) * 256 + o] = f2bf(val);
        else if (o < 256) k2t[((size_t)b * 4096 + p) * 256 + o] = f2bf(val);
        else v2[((size_t)b * 256 + (o - 256)) * 4096 + p] = f2bf(val);
      }
    }
  }
}

// ---------------- final: out = merge(op0,op1)@wout^T + bout + y1@wsk^T + bsk, f32 channel-major -------------
__launch_bounds__(256)
__global__ void gemm_final(const ushort* __restrict__ op0, const ushort* __restrict__ op1,
                           const float* __restrict__ ml, const ushort* __restrict__ y1t,
                           const ushort* __restrict__ woutb, const ushort* __restrict__ wskb,
                           const float* __restrict__ bout, const float* __restrict__ bsk,
                           float* __restrict__ out) {
  __shared__ ushort smem[32768];
  ushort* al0 = smem;            ushort* al1 = smem + 8192;
  ushort* bl0 = smem + 16384;    ushort* bl1 = smem + 24576;
  const int b = blockIdx.z;
  const int m0 = blockIdx.y * 128, n0 = blockIdx.x * 128;
  const int tid = threadIdx.x, w = tid >> 6, l = tid & 63;
  const int wr = w >> 1, wc = w & 1, lr = l & 15, lg = l >> 4;
  const float2* ml2 = (const float2*)ml;
  const ushort* A1 = y1t + (size_t)b * 4096 * 256;

  int rowj[4], colj[4], ldsj[4];
  float w0j[4], w1j[4];
#pragma unroll
  for (int j = 0; j < 4; ++j) {
    int chunk = (j * 4 + w) * 64 + l;
    int row = chunk >> 3, sl = chunk & 7;
    rowj[j] = row; colj[j] = sl * 8;
    ldsj[j] = row * 64 + ((sl * 8) ^ ((row & 7) << 3));
    float2 a = ml2[(size_t)b * 4096 + m0 + row];
    float2 c = ml2[(size_t)(4 + b) * 4096 + m0 + row];
    float m = fmaxf(a.x, c.x);
    float e0 = fexp2(a.x - m), e1 = fexp2(c.x - m);
    float inv = 1.f / (a.y * e0 + c.y * e1);
    w0j[j] = e0 * inv; w1j[j] = e1 * inv;
  }

  auto stageA_merge = [&](int ko, ushort* al) {
    uint4 r0[4], r1[4];
#pragma unroll
    for (int j = 0; j < 4; ++j) {
      size_t off = ((size_t)b * 4096 + m0 + rowj[j]) * 256 + ko + colj[j];
      r0[j] = *(const uint4*)(op0 + off);
      r1[j] = *(const uint4*)(op1 + off);
    }
#pragma unroll
    for (int j = 0; j < 4; ++j) {
      uint rr[4] = { r0[j].x, r0[j].y, r0[j].z, r0[j].w };
      uint ss[4] = { r1[j].x, r1[j].y, r1[j].z, r1[j].w };
      ushort o[8];
#pragma unroll
      for (int q = 0; q < 4; ++q) {
        o[q * 2]     = f2bf(bflo(rr[q]) * w0j[j] + bflo(ss[q]) * w1j[j]);
        o[q * 2 + 1] = f2bf(bfhi(rr[q]) * w0j[j] + bfhi(ss[q]) * w1j[j]);
      }
      uint4 wv;
      wv.x = (uint)o[0] | ((uint)o[1] << 16); wv.y = (uint)o[2] | ((uint)o[3] << 16);
      wv.z = (uint)o[4] | ((uint)o[5] << 16); wv.w = (uint)o[6] | ((uint)o[7] << 16);
      *(uint4*)&al[ldsj[j]] = wv;
    }
  };

  f32x4 acc[4][4] = {};
  stageA_merge(0, al0);
  g_stage_b(woutb, n0, 0, bl0, w, l);
  __syncthreads();
  for (int s = 0; s < 8; ++s) {
    int cur = s & 1;
    if (s + 1 < 8) {
      int ko = ((s + 1) & 3) * 64;
      ushort* an = cur ? al0 : al1;
      ushort* bn = cur ? bl0 : bl1;
      if (s + 1 < 4) stageA_merge(ko, an);
      else g_stage_a(A1, m0, ko, an, w, l);
      g_stage_b((s + 1 >= 4) ? wskb : woutb, n0, ko, bn, w, l);
    }
    g_compute(cur ? al1 : al0, cur ? bl1 : bl0, wr, wc, lr, lg, acc);
    __syncthreads();
  }
  float4* cl = (float4*)smem; // [128 o][32 f4]
#pragma unroll
  for (int n = 0; n < 4; ++n) {
    int o = wc * 64 + n * 16 + lr;
    float bv = bout[n0 + o] + bsk[n0 + o];
#pragma unroll
    for (int m = 0; m < 4; ++m) {
      int pf4 = wr * 16 + m * 4 + lg;
      f32x4 v = acc[m][n];
      float4 vv; vv.x = v[0] + bv; vv.y = v[1] + bv; vv.z = v[2] + bv; vv.w = v[3] + bv;
      cl[o * 32 + (pf4 ^ (o & 31))] = vv;
    }
  }
  __syncthreads();
  float4* og = (float4*)(out + ((size_t)b * 256 + n0) * 4096 + m0);
#pragma unroll
  for (int i = 0; i < 16; ++i) {
    int o = i * 8 + (tid >> 5);
    int f4 = tid & 31;
    og[(size_t)o * 1024 + f4] = cl[o * 32 + (f4 ^ (o & 31))];
  }
}

// ---------------- flash attention: 512-thread blocks, q-width 32/wave, in-block k-pair merge ----------------
// Grid 256 x 512 (8 waves = 2 waves/SIMD at 1 block/CU). Block: QBLK=128 (4 waves x 32 q) over 2048 k-rows.
// Wave-group g (waves 0-3 / 4-7) owns k-sub-range g*1024 with its OWN 80KB staging pipeline (160KB total).
// LDS bytes stay halved vs r6 (2.1 GB: wave-iters 256x32x8), wave count 2048 -> overlap restored (r9 lesson:
// q32+kh2 gave only 1024 waves = 1/SIMD). Group partials merged IN-BLOCK via LDS (no extra global buffers);
// global side stays 2-way kh merge (op0/op1 + mlbuf), gemm_final unchanged.
__launch_bounds__(512, 2)
__global__ void attn(const ushort* __restrict__ Q, const ushort* __restrict__ K,
                     const ushort* __restrict__ V, ushort* __restrict__ op0,
                     ushort* __restrict__ op1, float* __restrict__ ml) {
  __shared__ ushort lds[2][40960]; // per group: K 3x8192 @ 0, V 2x8192 @ 24576 (ushorts); 160 KB total
  const int bid = blockIdx.x;
  const int xcd = bid & 7, r = bid >> 3;
  const int b = xcd >> 1;
  const int kh = r & 1;
  const int qt = (xcd & 1) * 16 + (r >> 1);   // 0..31, QBLK=128
  const int tid = threadIdx.x;
  const int w = tid >> 6, l = tid & 63;
  const int g = w >> 2, wg = w & 3;
  const int lr = l & 15, lg = l >> 4;

  const ushort* Qb = Q + (size_t)b * 4096 * 256;
  const ushort* Kb = K + (size_t)b * 4096 * 256 + (size_t)(kh * 2048 + g * 1024) * 256;
  const ushort* Vb = V + (size_t)b * 256 * 4096 + kh * 2048 + g * 1024;

  ushort* kbuf = lds[g];
  ushort* vbuf = lds[g] + 24576;

  int kOff[4], vOff[4];
#pragma unroll
  for (int j = 0; j < 4; ++j) {
    int c = (j * 4 + wg) * 64 + l;
    int krow = c >> 5, ksl = c & 31;
    kOff[j] = krow * 256 + ((ksl * 8) ^ ((krow & 15) << 4));
    int R = c >> 2, CH = c & 3;
    int vd = R ^ ((R >> 1) & 1);
    int gch = CH ^ ((R >> 1) & 3);
    vOff[j] = vd * 4096 + gch * 8;
  }
  auto stageK = [&](int kt, ushort* dst) {
#pragma unroll
    for (int j = 0; j < 4; ++j)
      gload16(Kb + (size_t)kt * 8192 + kOff[j], dst + (j * 4 + wg) * 512);
  };
  auto stageV = [&](int kt, ushort* dst) {
#pragma unroll
    for (int j = 0; j < 4; ++j)
      gload16(Vb + (size_t)kt * 32 + vOff[j], dst + (j * 4 + wg) * 512);
  };

  // two Q fragment sets straight to registers (rows shared by both groups)
  bf16x8 qfA[8], qfB[8];
  {
    const ushort* qa = Qb + (size_t)(qt * 128 + wg * 32 + lr) * 256 + lg * 8;
    const ushort* qc = qa + 16 * 256;
#pragma unroll
    for (int kk = 0; kk < 8; ++kk) {
      qfA[kk] = *(const bf16x8*)(qa + kk * 32);
      qfB[kk] = *(const bf16x8*)(qc + kk * 32);
    }
  }

  stageK(0, kbuf);
  stageV(0, vbuf);
  stageK(1, kbuf + 8192);
  asm volatile("s_waitcnt vmcnt(4)" ::: "memory");
  __builtin_amdgcn_s_barrier();

  const int lrp = lr ^ ((lr >> 1) & 1);
  const int vsw = (lr >> 1) & 3;
  const int vbase0 = lrp * 32 + (((lg >> 1)) ^ vsw) * 8 + (lg & 1) * 4;
  const int vbase1 = lrp * 32 + ((2 + (lg >> 1)) ^ vsw) * 8 + (lg & 1) * 4;

  float mA = -1e30f, lsA = 0.f, mB = -1e30f, lsB = 0.f;
  f32x4 oaccA[16] = {}, oaccB[16] = {};
  int kc = 0, kn2 = 2;

  for (int kt = 0; kt < 32; ++kt) {
    const ushort* kl = kbuf + kc * 8192;
    const ushort* vl = vbuf + (kt & 1) * 8192;

    __builtin_amdgcn_s_setprio(1);
    f32x4 sA[2] = {}, sB[2] = {};
#pragma unroll
    for (int kk = 0; kk < 8; ++kk) {
#pragma unroll
      for (int n = 0; n < 2; ++n) {
        bf16x8 kv = *(const bf16x8*)&kl[(n * 16 + lr) * 256 + ((kk * 32 + lg * 8) ^ (lr << 4))];
        sA[n] = __builtin_amdgcn_mfma_f32_16x16x32_bf16(kv, qfA[kk], sA[n], 0, 0, 0);
        sB[n] = __builtin_amdgcn_mfma_f32_16x16x32_bf16(kv, qfB[kk], sB[n], 0, 0, 0);
      }
    }
    __builtin_amdgcn_s_setprio(0);

    if (kt + 1 < 32) stageV(kt + 1, vbuf + ((kt + 1) & 1) * 8192);
    if (kt + 2 < 32) stageK(kt + 2, kbuf + kn2 * 8192);

    float tmA = fmaxf(fmaxf(fmaxf(sA[0][0], sA[0][1]), fmaxf(sA[0][2], sA[0][3])),
                      fmaxf(fmaxf(sA[1][0], sA[1][1]), fmaxf(sA[1][2], sA[1][3])));
    tmA = fmaxf(tmA, __shfl_xor(tmA, 16));
    tmA = fmaxf(tmA, __shfl_xor(tmA, 32));
    float tmB = fmaxf(fmaxf(fmaxf(sB[0][0], sB[0][1]), fmaxf(sB[0][2], sB[0][3])),
                      fmaxf(fmaxf(sB[1][0], sB[1][1]), fmaxf(sB[1][2], sB[1][3])));
    tmB = fmaxf(tmB, __shfl_xor(tmB, 16));
    tmB = fmaxf(tmB, __shfl_xor(tmB, 32));

    if (__any((tmA > mA + 11.5f) || (tmB > mB + 11.5f))) { // defer-max
      {
        float mn = fmaxf(mA, tmA);
        float al = fexp2(mA - mn);
        mA = mn; lsA *= al;
        float ar[4];
#pragma unroll
        for (int r2 = 0; r2 < 4; ++r2) ar[r2] = __shfl(al, lg * 4 + r2);
#pragma unroll
        for (int nf = 0; nf < 16; ++nf)
#pragma unroll
          for (int r2 = 0; r2 < 4; ++r2) oaccA[nf][r2] *= ar[r2];
      }
      {
        float mn = fmaxf(mB, tmB);
        float al = fexp2(mB - mn);
        mB = mn; lsB *= al;
        float ar[4];
#pragma unroll
        for (int r2 = 0; r2 < 4; ++r2) ar[r2] = __shfl(al, lg * 4 + r2);
#pragma unroll
        for (int nf = 0; nf < 16; ++nf)
#pragma unroll
          for (int r2 = 0; r2 < 4; ++r2) oaccB[nf][r2] *= ar[r2];
      }
    }

    uint pwA[2][2], pwB[2][2];
#pragma unroll
    for (int n = 0; n < 2; ++n) {
      float a0 = fexp2(sA[n][0] - mA), a1 = fexp2(sA[n][1] - mA);
      float a2 = fexp2(sA[n][2] - mA), a3 = fexp2(sA[n][3] - mA);
      lsA += (a0 + a1) + (a2 + a3);
      asm("v_cvt_pk_bf16_f32 %0, %1, %2" : "=v"(pwA[n][0]) : "v"(a0), "v"(a1));
      asm("v_cvt_pk_bf16_f32 %0, %1, %2" : "=v"(pwA[n][1]) : "v"(a2), "v"(a3));
      float b0 = fexp2(sB[n][0] - mB), b1 = fexp2(sB[n][1] - mB);
      float b2 = fexp2(sB[n][2] - mB), b3 = fexp2(sB[n][3] - mB);
      lsB += (b0 + b1) + (b2 + b3);
      asm("v_cvt_pk_bf16_f32 %0, %1, %2" : "=v"(pwB[n][0]) : "v"(b0), "v"(b1));
      asm("v_cvt_pk_bf16_f32 %0, %1, %2" : "=v"(pwB[n][1]) : "v"(b2), "v"(b3));
    }

    __builtin_amdgcn_s_setprio(1);
#pragma unroll
    for (int n = 0; n < 2; ++n) {
      uint2 ua; ua.x = pwA[n][0]; ua.y = pwA[n][1];
      s16x4 paA = __builtin_bit_cast(s16x4, ua);
      uint2 ub; ub.x = pwB[n][0]; ub.y = pwB[n][1];
      s16x4 paB = __builtin_bit_cast(s16x4, ub);
      const int vbase = n ? vbase1 : vbase0;
#pragma unroll
      for (int nf = 0; nf < 16; ++nf) {
        s16x4 vv = *(const s16x4*)&vl[nf * 512 + vbase];
        mfma16(oaccA[nf], paA, vv);
        mfma16(oaccB[nf], paB, vv);
      }
    }
    __builtin_amdgcn_s_setprio(0);

    if (kt < 31) {
      if (kt < 30) asm volatile("s_waitcnt vmcnt(4)" ::: "memory");
      else         asm volatile("s_waitcnt vmcnt(0)" ::: "memory");
      __builtin_amdgcn_s_barrier();
    }
    kc = (kc == 2) ? 0 : kc + 1;
    kn2 = (kn2 == 2) ? 0 : kn2 + 1;
  }

  // cross-lg row-sum reduce (each lane then holds row stats for q row wg*32+lr / +16)
  float ra = lsA; ra += __shfl_xor(ra, 16); ra += __shfl_xor(ra, 32);
  float rb = lsB; rb += __shfl_xor(rb, 16); rb += __shfl_xor(rb, 32);

  __syncthreads(); // all loop LDS reads complete before repurposing buffers

  ushort* po = lds[0];               // [128 q][256 d] bf16 partial from group 1 (64 KB)
  float* mlm = (float*)&lds[1][0];   // [128] m
  float* mll = mlm + 128;            // [128] l

  if (g == 1) {
    if (lg == 0) {
      mlm[wg * 32 + lr] = mA;       mll[wg * 32 + lr] = ra;
      mlm[wg * 32 + 16 + lr] = mB;  mll[wg * 32 + 16 + lr] = rb;
    }
#pragma unroll
    for (int nf = 0; nf < 16; ++nf)
#pragma unroll
      for (int r2 = 0; r2 < 4; ++r2) {
        int ql = wg * 32 + lg * 4 + r2;
        po[ql * 256 + nf * 16 + lr] = f2bf(oaccA[nf][r2]);
        po[(ql + 16) * 256 + nf * 16 + lr] = f2bf(oaccB[nf][r2]);
      }
  }
  __syncthreads();
  if (g == 0) {
    // per-lane stats for rows wg*32+lr (set A) and +16 (set B)
    float mpA = mlm[wg * 32 + lr],      lpA = mll[wg * 32 + lr];
    float mpB = mlm[wg * 32 + 16 + lr], lpB = mll[wg * 32 + 16 + lr];
    float msA = fmaxf(mA, mpA);
    float fa = fexp2(mA - msA), fb = fexp2(mpA - msA);
    float lmA = ra * fa + lpA * fb;
    float msB = fmaxf(mB, mpB);
    float fa2 = fexp2(mB - msB), fb2 = fexp2(mpB - msB);
    float lmB = rb * fa2 + lpB * fb2;
    if (lg == 0) {
      float2* ml2 = (float2*)ml;
      int qp = qt * 128 + wg * 32 + lr;
      float2 va; va.x = msA; va.y = lmA;
      ml2[((size_t)(kh * 4 + b)) * 4096 + qp] = va;
      float2 vc; vc.x = msB; vc.y = lmB;
      ml2[((size_t)(kh * 4 + b)) * 4096 + qp + 16] = vc;
    }
    float far[4], fbr[4], fa2r[4], fb2r[4];
#pragma unroll
    for (int r2 = 0; r2 < 4; ++r2) {
      far[r2] = __shfl(fa, lg * 4 + r2);   fbr[r2] = __shfl(fb, lg * 4 + r2);
      fa2r[r2] = __shfl(fa2, lg * 4 + r2); fb2r[r2] = __shfl(fb2, lg * 4 + r2);
    }
    ushort* Ob = (kh ? op1 : op0) + (size_t)b * 4096 * 256;
#pragma unroll
    for (int nf = 0; nf < 16; ++nf)
#pragma unroll
      for (int r2 = 0; r2 < 4; ++r2) {
        int ql = wg * 32 + lg * 4 + r2;
        float v1 = oaccA[nf][r2] * far[r2] + bflo((uint)po[ql * 256 + nf * 16 + lr]) * fbr[r2];
        Ob[(size_t)(qt * 128 + ql) * 256 + nf * 16 + lr] = f2bf(v1);
        float v2 = oaccB[nf][r2] * fa2r[r2] + bflo((uint)po[(ql + 16) * 256 + nf * 16 + lr]) * fb2r[r2];
        Ob[(size_t)(qt * 128 + ql + 16) * 256 + nf * 16 + lr] = f2bf(v2);
      }
  }
}

extern "C" void kernel_launch(void* const* d_in, const int* in_sizes, int n_in,
                              void* d_out, int out_size, void* d_ws, size_t ws_size,
                              hipStream_t stream) {
  const float* x1 = (const float*)d_in[0];
  const float* x2 = (const float*)d_in[1];
  const float* w1 = (const float*)d_in[2];
  const float* b1 = (const float*)d_in[3];
  const float* w2 = (const float*)d_in[4];
  const float* b2 = (const float*)d_in[5];
  const float* gn_w = (const float*)d_in[6];
  const float* gn_b = (const float*)d_in[7];
  const float* wqkv = (const float*)d_in[8];
  const float* wout = (const float*)d_in[9];
  const float* bout = (const float*)d_in[10];
  const float* wsk = (const float*)d_in[11];
  const float* bsk = (const float*)d_in[12];
  float* out = (float*)d_out;

  const size_t NB = (size_t)4 * 4096 * 256;
  ushort* x1t = (ushort*)d_ws;      // later reused as q1t
  ushort* x2t = x1t + NB;           // later reused as k2t
  ushort* y1t = x2t + NB;           // persists (skip input)
  ushort* y2t = y1t + NB;           // GN'd in place -> g2t; later reused as O-partial kh=0
  ushort* g1t = y2t + NB;           // later reused as O-partial kh=1
  ushort* v2  = g1t + NB;
  ushort* w1b = v2 + NB;
  ushort* w2b = w1b + 65536;
  ushort* wqb = w2b + 65536;
  ushort* wkvb = wqb + 65536;       // 131072
  ushort* woutb = wkvb + 131072;
  ushort* wskb = woutb + 65536;
  float* mlbuf = (float*)(wskb + 65536); // 2*4*4096 float2

  cast_transpose<<<dim3(128, 8, 8), dim3(32, 8), 0, stream>>>(x1, x2, x1t, x2t);
  cast_weights<<<1792, 256, 0, stream>>>(w1, w2, wqkv, wout, wsk,
                                         w1b, w2b, wqb, wkvb, woutb, wskb);
  conv_pair<<<dim3(2, 32, 8), 256, 0, stream>>>(x1t, x2t, w1b, w2b, b1, b2, y1t, y2t);
  groupnorm<<<dim3(32, 4, 2), 256, 0, stream>>>(y1t, g1t, y2t, gn_w, gn_b);
  gemm_qkv<<<dim3(6, 32, 4), 256, 0, stream>>>(g1t, y2t, wqb, wkvb, x1t, x2t, v2);
  attn<<<256, 512, 0, stream>>>(x1t, x2t, v2, y2t, g1t, mlbuf);
  gemm_final<<<dim3(2, 32, 4), 256, 0, stream>>>(y2t, g1t, mlbuf, y1t, woutb, wskb, bout, bsk, out);
}

// Round 11
// 226.520 us; speedup vs baseline: 1.1569x; 1.0178x over previous
//
#include <hip/hip_runtime.h>

typedef unsigned int uint;
typedef unsigned short ushort;
typedef __bf16 bf16x8 __attribute__((ext_vector_type(8)));
typedef short s16x4 __attribute__((ext_vector_type(4)));
typedef float f32x4 __attribute__((ext_vector_type(4)));

__device__ __forceinline__ ushort f2bf(float f) {
  union { float f; uint u; } c; c.f = f;
  uint u = c.u + 0x7fffu + ((c.u >> 16) & 1u);
  return (ushort)(u >> 16);
}
__device__ __forceinline__ float bflo(uint u) { union { uint u; float f; } c; c.u = u << 16; return c.f; }
__device__ __forceinline__ float bfhi(uint u) { union { uint u; float f; } c; c.u = u & 0xffff0000u; return c.f; }

__device__ __forceinline__ void gload16(const void* g, void* l) {
  __builtin_amdgcn_global_load_lds((const __attribute__((address_space(1))) void*)g,
                                   (__attribute__((address_space(3))) void*)l, 16, 0, 0);
}
__device__ __forceinline__ void mfma16(f32x4& acc, s16x4 a, s16x4 b) {
  asm("v_mfma_f32_16x16x16_bf16 %0, %1, %2, %0" : "+v"(acc) : "v"(a), "v"(b));
}
__device__ __forceinline__ float fexp2(float x) {
  float y; asm("v_exp_f32 %0, %1" : "=v"(y) : "v"(x)); return y;
}

// ---------------- cast + transpose: x [B][C][4096] f32 -> xt [B][4096][C] bf16 (both tensors) ----------------
__global__ void cast_transpose(const float* __restrict__ x1, const float* __restrict__ x2,
                               ushort* __restrict__ x1t, ushort* __restrict__ x2t) {
  __shared__ float t[32][33];
  const int z = blockIdx.z, b = z & 3, tn = z >> 2;
  const float* x = tn ? x2 : x1;
  ushort* xt = tn ? x2t : x1t;
  const int pc = blockIdx.x, cc = blockIdx.y;
  const int tx = threadIdx.x, ty = threadIdx.y; // 32 x 8
  const float* xb = x + ((size_t)b * 256 + cc * 32) * 4096 + pc * 32;
#pragma unroll
  for (int i = 0; i < 4; ++i)
    t[ty * 4 + i][tx] = xb[(size_t)(ty * 4 + i) * 4096 + tx];
  __syncthreads();
  ushort* xtb = xt + ((size_t)b * 4096 + pc * 32) * 256 + cc * 32;
#pragma unroll
  for (int i = 0; i < 4; ++i)
    xtb[(size_t)(ty * 4 + i) * 256 + tx] = f2bf(t[tx][ty * 4 + i]);
}

// ---------------- all weights -> bf16, one kernel. Q weights get 1/sqrt(C)*log2(e) folded in. ----------------
__global__ void cast_weights(const float* __restrict__ w1, const float* __restrict__ w2,
                             const float* __restrict__ wqkv, const float* __restrict__ wout,
                             const float* __restrict__ wsk,
                             ushort* __restrict__ w1b, ushort* __restrict__ w2b,
                             ushort* __restrict__ wqb, ushort* __restrict__ wkvb,
                             ushort* __restrict__ woutb, ushort* __restrict__ wskb) {
  const int i = blockIdx.x * 256 + threadIdx.x;
  const float QS = 0.0625f * 1.44269504088896f;
  if (i < 65536) w1b[i] = f2bf(w1[i]);
  else if (i < 131072) w2b[i - 65536] = f2bf(w2[i - 65536]);
  else if (i < 196608) wqb[i - 131072] = f2bf(wqkv[i - 131072] * QS);
  else if (i < 327680) wkvb[i - 196608] = f2bf(wqkv[i - 131072]);
  else if (i < 393216) woutb[i - 327680] = f2bf(wout[i - 327680]);
  else wskb[i - 393216] = f2bf(wsk[i - 393216]);
}

// ---------------- GroupNorm on pixel-major bf16 [B][4096][256], G=32 (8 ch/group); z selects tensor ----------------
__global__ void groupnorm(const ushort* __restrict__ y1, ushort* __restrict__ o1,
                          const ushort* __restrict__ y2,
                          const float* __restrict__ gamma, const float* __restrict__ beta) {
  const int g = blockIdx.x, b = blockIdx.y, tn = blockIdx.z;
  const ushort* y = tn ? y2 : y1;
  ushort* gout = tn ? (ushort*)y2 : o1;
  const int tid = threadIdx.x; // 256
  const size_t base = ((size_t)b * 4096) * 256 + g * 8;
  float s = 0.f, ss = 0.f;
#pragma unroll
  for (int i = 0; i < 16; ++i) {
    int p = i * 256 + tid;
    uint4 raw = *(const uint4*)(y + base + (size_t)p * 256);
    float v0 = bflo(raw.x), v1 = bfhi(raw.x), v2 = bflo(raw.y), v3 = bfhi(raw.y);
    float v4 = bflo(raw.z), v5 = bfhi(raw.z), v6 = bflo(raw.w), v7 = bfhi(raw.w);
    s += v0 + v1 + v2 + v3 + v4 + v5 + v6 + v7;
    ss += v0 * v0 + v1 * v1 + v2 * v2 + v3 * v3 + v4 * v4 + v5 * v5 + v6 * v6 + v7 * v7;
  }
#pragma unroll
  for (int off = 1; off < 64; off <<= 1) { s += __shfl_xor(s, off); ss += __shfl_xor(ss, off); }
  __shared__ float red[10];
  if ((tid & 63) == 0) { red[tid >> 6] = s; red[4 + (tid >> 6)] = ss; }
  __syncthreads();
  if (tid == 0) {
    float S = red[0] + red[1] + red[2] + red[3];
    float SS = red[4] + red[5] + red[6] + red[7];
    float mu = S * (1.f / 32768.f);
    float var = SS * (1.f / 32768.f) - mu * mu;
    red[8] = mu; red[9] = rsqrtf(var + 1e-5f);
  }
  __syncthreads();
  const float mu = red[8], rstd = red[9];
  float ga[8], be[8];
#pragma unroll
  for (int j = 0; j < 8; ++j) { ga[j] = gamma[g * 8 + j]; be[j] = beta[g * 8 + j]; }
#pragma unroll
  for (int i = 0; i < 16; ++i) {
    int p = i * 256 + tid;
    const size_t off = base + (size_t)p * 256;
    uint4 raw = *(const uint4*)(y + off);
    float v[8] = { bflo(raw.x), bfhi(raw.x), bflo(raw.y), bfhi(raw.y),
                   bflo(raw.z), bfhi(raw.z), bflo(raw.w), bfhi(raw.w) };
    ushort o[8];
#pragma unroll
    for (int j = 0; j < 8; ++j) o[j] = f2bf((v[j] - mu) * rstd * ga[j] + be[j]);
    uint4 w;
    w.x = (uint)o[0] | ((uint)o[1] << 16); w.y = (uint)o[2] | ((uint)o[3] << 16);
    w.z = (uint)o[4] | ((uint)o[5] << 16); w.w = (uint)o[6] | ((uint)o[7] << 16);
    *(uint4*)(gout + off) = w;
  }
}

// ---------------- shared GEMM pieces: 64x128 tile, K-step 64, double-buffered LDS ----------------
// A-tile [64 m][64 k] (8KB), B-tile [128 n][64 k] (16KB). 4 waves: wave w owns o in [w*32, w*32+32).
__device__ __forceinline__ void g_stage_a64(const ushort* __restrict__ A,
                                            int m0, int ko, ushort* al, int w, int l) {
#pragma unroll
  for (int j = 0; j < 2; ++j) {
    int cb = (j * 4 + w) * 64;
    int chunk = cb + l;                 // 0..511
    int row = chunk >> 3, sl = chunk & 7;
    int col = (sl * 8) ^ ((row & 7) << 3);
    gload16(A + (size_t)(m0 + row) * 256 + ko + col, al + chunk * 8);
  }
}

__device__ __forceinline__ void g_stage_b64(const ushort* __restrict__ W,
                                            int n0, int ko, ushort* bl, int w, int l) {
#pragma unroll
  for (int j = 0; j < 4; ++j) {
    int cb = (j * 4 + w) * 64;
    int chunk = cb + l;                 // 0..1023
    int row = chunk >> 3, sl = chunk & 7;
    int col = (sl * 8) ^ ((row & 7) << 3);
    gload16(W + (size_t)(n0 + row) * 256 + ko + col, bl + chunk * 8);
  }
}

__device__ __forceinline__ void g_compute64(const ushort* al, const ushort* bl,
                                            int w, int lr, int lg, f32x4 acc[4][2]) {
#pragma unroll
  for (int kk = 0; kk < 2; ++kk) {
    bf16x8 af[4], bfr[2];
#pragma unroll
    for (int m = 0; m < 4; ++m)
      af[m] = *(const bf16x8*)&al[(m * 16 + lr) * 64 + ((kk * 32 + lg * 8) ^ ((lr & 7) << 3))];
#pragma unroll
    for (int n = 0; n < 2; ++n)
      bfr[n] = *(const bf16x8*)&bl[(w * 32 + n * 16 + lr) * 64 + ((kk * 32 + lg * 8) ^ ((lr & 7) << 3))];
#pragma unroll
    for (int m = 0; m < 4; ++m)
#pragma unroll
      for (int n = 0; n < 2; ++n)
        acc[m][n] = __builtin_amdgcn_mfma_f32_16x16x32_bf16(af[m], bfr[n], acc[m][n], 0, 0, 0);
  }
}

// ---------------- conv1 + conv2 fused: z = t*4 + b; 64x128 tiles, 48KB LDS -> 3 blocks/CU ----------------
__launch_bounds__(256)
__global__ void conv_pair(const ushort* __restrict__ x1t, const ushort* __restrict__ x2t,
                          const ushort* __restrict__ w1b, const ushort* __restrict__ w2b,
                          const float* __restrict__ b1, const float* __restrict__ b2,
                          ushort* __restrict__ y1t, ushort* __restrict__ y2t) {
  __shared__ ushort al[2][4096];
  __shared__ ushort bl[2][8192];
  const int z = blockIdx.z, b = z & 3, t = z >> 2;
  const ushort* A = (t ? x2t : x1t) + (size_t)b * 4096 * 256;
  const ushort* W = t ? w2b : w1b;
  const float* bias = t ? b2 : b1;
  ushort* out = t ? y2t : y1t;
  const int m0 = blockIdx.y * 64, n0 = blockIdx.x * 128;
  const int tid = threadIdx.x, w = tid >> 6, l = tid & 63;
  const int lr = l & 15, lg = l >> 4;
  f32x4 acc[4][2] = {};
  g_stage_a64(A, m0, 0, al[0], w, l);
  g_stage_b64(W, n0, 0, bl[0], w, l);
  __syncthreads();
  for (int s = 0; s < 4; ++s) {
    int cur = s & 1;
    if (s + 1 < 4) {
      g_stage_a64(A, m0, (s + 1) * 64, al[cur ^ 1], w, l);
      g_stage_b64(W, n0, (s + 1) * 64, bl[cur ^ 1], w, l);
    }
    g_compute64(al[cur], bl[cur], w, lr, lg, acc);
    __syncthreads();
  }
#pragma unroll
  for (int n = 0; n < 2; ++n) {
    int o = n0 + w * 32 + n * 16 + lr;
    float bv = bias[o];
#pragma unroll
    for (int m = 0; m < 4; ++m) {
      int p0 = m0 + m * 16 + lg * 4;
#pragma unroll
      for (int r = 0; r < 4; ++r)
        out[((size_t)b * 4096 + p0 + r) * 256 + o] = f2bf(acc[m][n][r] + bv);
    }
  }
}

// ---------------- q-proj + kv-proj fused: x<2 -> q1 (from g1t), x>=2 -> [k2|v2] (from y2t) ----------------
__launch_bounds__(256)
__global__ void gemm_qkv(const ushort* __restrict__ g1t, const ushort* __restrict__ y2t,
                         const ushort* __restrict__ wqb, const ushort* __restrict__ wkvb,
                         ushort* __restrict__ q1t, ushort* __restrict__ k2t, ushort* __restrict__ v2) {
  __shared__ ushort al[2][4096];
  __shared__ ushort bl[2][8192];
  const int b = blockIdx.z, x = blockIdx.x;
  const bool isq = x < 2;
  const ushort* A = (isq ? g1t : y2t) + (size_t)b * 4096 * 256;
  const ushort* W = isq ? wqb : wkvb;
  const int n0 = isq ? x * 128 : (x - 2) * 128;
  const int m0 = blockIdx.y * 64;
  const int tid = threadIdx.x, w = tid >> 6, l = tid & 63;
  const int lr = l & 15, lg = l >> 4;
  f32x4 acc[4][2] = {};
  g_stage_a64(A, m0, 0, al[0], w, l);
  g_stage_b64(W, n0, 0, bl[0], w, l);
  __syncthreads();
  for (int s = 0; s < 4; ++s) {
    int cur = s & 1;
    if (s + 1 < 4) {
      g_stage_a64(A, m0, (s + 1) * 64, al[cur ^ 1], w, l);
      g_stage_b64(W, n0, (s + 1) * 64, bl[cur ^ 1], w, l);
    }
    g_compute64(al[cur], bl[cur], w, lr, lg, acc);
    __syncthreads();
  }
#pragma unroll
  for (int n = 0; n < 2; ++n) {
    int o = n0 + w * 32 + n * 16 + lr;
#pragma unroll
    for (int m = 0; m < 4; ++m) {
      int p0 = m0 + m * 16 + lg * 4;
#pragma unroll
      for (int r = 0; r < 4; ++r) {
        float val = acc[m][n][r];
        int p = p0 + r;
        if (isq) q1t[((size_t)b * 4096 + p) * 256 + o] = f2bf(val);
        else if (o < 256) k2t[((size_t)b * 4096 + p) * 256 + o] = f2bf(val);
        else v2[((size_t)b * 256 + (o - 256)) * 4096 + p] = f2bf(val);
      }
    }
  }
}

// ---------------- final: out = merge(op0,op1)@wout^T + bout + y1@wsk^T + bsk, f32 channel-major -------------
// M-tile 64 -> 512 blocks (2 waves/SIMD, was 1). Attn k-half merge fused into the wout-pass A-stage.
__launch_bounds__(256)
__global__ void gemm_final(const ushort* __restrict__ op0, const ushort* __restrict__ op1,
                           const float* __restrict__ ml, const ushort* __restrict__ y1t,
                           const ushort* __restrict__ woutb, const ushort* __restrict__ wskb,
                           const float* __restrict__ bout, const float* __restrict__ bsk,
                           float* __restrict__ out) {
  __shared__ ushort smem[24576]; // al0 4096, al1 4096, bl0 8192, bl1 8192 (ushorts) = 48KB
  ushort* al0 = smem;            ushort* al1 = smem + 4096;
  ushort* bl0 = smem + 8192;     ushort* bl1 = smem + 16384;
  const int b = blockIdx.z;
  const int m0 = blockIdx.y * 64, n0 = blockIdx.x * 128;
  const int tid = threadIdx.x, w = tid >> 6, l = tid & 63;
  const int lr = l & 15, lg = l >> 4;
  const float2* ml2 = (const float2*)ml;
  const ushort* A1 = y1t + (size_t)b * 4096 * 256;

  // per-thread A-stage chunk geometry + merge weights (row-dependent, k-step-invariant)
  int rowj[2], colj[2], ldsj[2];
  float w0j[2], w1j[2];
#pragma unroll
  for (int j = 0; j < 2; ++j) {
    int chunk = (j * 4 + w) * 64 + l;
    int row = chunk >> 3, sl = chunk & 7;
    rowj[j] = row; colj[j] = sl * 8;
    ldsj[j] = row * 64 + ((sl * 8) ^ ((row & 7) << 3));
    float2 a = ml2[(size_t)b * 4096 + m0 + row];
    float2 c = ml2[(size_t)(4 + b) * 4096 + m0 + row];
    float m = fmaxf(a.x, c.x);
    float e0 = fexp2(a.x - m), e1 = fexp2(c.x - m);
    float inv = 1.f / (a.y * e0 + c.y * e1);
    w0j[j] = e0 * inv; w1j[j] = e1 * inv;
  }

  auto stageA_merge = [&](int ko, ushort* al) {
    uint4 r0[2], r1[2];
#pragma unroll
    for (int j = 0; j < 2; ++j) {
      size_t off = ((size_t)b * 4096 + m0 + rowj[j]) * 256 + ko + colj[j];
      r0[j] = *(const uint4*)(op0 + off);
      r1[j] = *(const uint4*)(op1 + off);
    }
#pragma unroll
    for (int j = 0; j < 2; ++j) {
      uint rr[4] = { r0[j].x, r0[j].y, r0[j].z, r0[j].w };
      uint ss[4] = { r1[j].x, r1[j].y, r1[j].z, r1[j].w };
      ushort o[8];
#pragma unroll
      for (int q = 0; q < 4; ++q) {
        o[q * 2]     = f2bf(bflo(rr[q]) * w0j[j] + bflo(ss[q]) * w1j[j]);
        o[q * 2 + 1] = f2bf(bfhi(rr[q]) * w0j[j] + bfhi(ss[q]) * w1j[j]);
      }
      uint4 wv;
      wv.x = (uint)o[0] | ((uint)o[1] << 16); wv.y = (uint)o[2] | ((uint)o[3] << 16);
      wv.z = (uint)o[4] | ((uint)o[5] << 16); wv.w = (uint)o[6] | ((uint)o[7] << 16);
      *(uint4*)&al[ldsj[j]] = wv;
    }
  };

  f32x4 acc[4][2] = {};
  stageA_merge(0, al0);
  g_stage_b64(woutb, n0, 0, bl0, w, l);
  __syncthreads();
  for (int s = 0; s < 8; ++s) {
    int cur = s & 1;
    if (s + 1 < 8) {
      int ko = ((s + 1) & 3) * 64;
      ushort* an = cur ? al0 : al1;
      ushort* bn = cur ? bl0 : bl1;
      if (s + 1 < 4) stageA_merge(ko, an);
      else g_stage_a64(A1, m0, ko, an, w, l);
      g_stage_b64((s + 1 >= 4) ? wskb : woutb, n0, ko, bn, w, l);
    }
    g_compute64(cur ? al1 : al0, cur ? bl1 : bl0, w, lr, lg, acc);
    __syncthreads();
  }
  // epilogue: bias, LDS transpose bounce (swizzled), coalesced f32 writes
  float4* cl = (float4*)smem; // [128 o][16 f4] = 32KB, fits in the 48KB smem
#pragma unroll
  for (int n = 0; n < 2; ++n) {
    int o = w * 32 + n * 16 + lr;
    float bv = bout[n0 + o] + bsk[n0 + o];
#pragma unroll
    for (int m = 0; m < 4; ++m) {
      int pf4 = m * 4 + lg;
      f32x4 v = acc[m][n];
      float4 vv; vv.x = v[0] + bv; vv.y = v[1] + bv; vv.z = v[2] + bv; vv.w = v[3] + bv;
      cl[o * 16 + (pf4 ^ (o & 15))] = vv;
    }
  }
  __syncthreads();
  float4* og = (float4*)(out + ((size_t)b * 256 + n0) * 4096 + m0);
#pragma unroll
  for (int i = 0; i < 8; ++i) {
    int o = i * 16 + (tid >> 4);
    int f4 = tid & 15;
    og[(size_t)o * 1024 + f4] = cl[o * 16 + (f4 ^ (o & 15))];
  }
}

// ---------------- flash attention: 512-thread blocks, q-width 32/wave, in-block k-pair merge ----------------
// (unchanged from round 10: 115.5 us, MfmaUtil 36.7%, 2 waves/SIMD)
__launch_bounds__(512, 2)
__global__ void attn(const ushort* __restrict__ Q, const ushort* __restrict__ K,
                     const ushort* __restrict__ V, ushort* __restrict__ op0,
                     ushort* __restrict__ op1, float* __restrict__ ml) {
  __shared__ ushort lds[2][40960]; // per group: K 3x8192 @ 0, V 2x8192 @ 24576 (ushorts); 160 KB total
  const int bid = blockIdx.x;
  const int xcd = bid & 7, r = bid >> 3;
  const int b = xcd >> 1;
  const int kh = r & 1;
  const int qt = (xcd & 1) * 16 + (r >> 1);   // 0..31, QBLK=128
  const int tid = threadIdx.x;
  const int w = tid >> 6, l = tid & 63;
  const int g = w >> 2, wg = w & 3;
  const int lr = l & 15, lg = l >> 4;

  const ushort* Qb = Q + (size_t)b * 4096 * 256;
  const ushort* Kb = K + (size_t)b * 4096 * 256 + (size_t)(kh * 2048 + g * 1024) * 256;
  const ushort* Vb = V + (size_t)b * 256 * 4096 + kh * 2048 + g * 1024;

  ushort* kbuf = lds[g];
  ushort* vbuf = lds[g] + 24576;

  int kOff[4], vOff[4];
#pragma unroll
  for (int j = 0; j < 4; ++j) {
    int c = (j * 4 + wg) * 64 + l;
    int krow = c >> 5, ksl = c & 31;
    kOff[j] = krow * 256 + ((ksl * 8) ^ ((krow & 15) << 4));
    int R = c >> 2, CH = c & 3;
    int vd = R ^ ((R >> 1) & 1);
    int gch = CH ^ ((R >> 1) & 3);
    vOff[j] = vd * 4096 + gch * 8;
  }
  auto stageK = [&](int kt, ushort* dst) {
#pragma unroll
    for (int j = 0; j < 4; ++j)
      gload16(Kb + (size_t)kt * 8192 + kOff[j], dst + (j * 4 + wg) * 512);
  };
  auto stageV = [&](int kt, ushort* dst) {
#pragma unroll
    for (int j = 0; j < 4; ++j)
      gload16(Vb + (size_t)kt * 32 + vOff[j], dst + (j * 4 + wg) * 512);
  };

  // two Q fragment sets straight to registers (rows shared by both groups)
  bf16x8 qfA[8], qfB[8];
  {
    const ushort* qa = Qb + (size_t)(qt * 128 + wg * 32 + lr) * 256 + lg * 8;
    const ushort* qc = qa + 16 * 256;
#pragma unroll
    for (int kk = 0; kk < 8; ++kk) {
      qfA[kk] = *(const bf16x8*)(qa + kk * 32);
      qfB[kk] = *(const bf16x8*)(qc + kk * 32);
    }
  }

  stageK(0, kbuf);
  stageV(0, vbuf);
  stageK(1, kbuf + 8192);
  asm volatile("s_waitcnt vmcnt(4)" ::: "memory");
  __builtin_amdgcn_s_barrier();

  const int lrp = lr ^ ((lr >> 1) & 1);
  const int vsw = (lr >> 1) & 3;
  const int vbase0 = lrp * 32 + (((lg >> 1)) ^ vsw) * 8 + (lg & 1) * 4;
  const int vbase1 = lrp * 32 + ((2 + (lg >> 1)) ^ vsw) * 8 + (lg & 1) * 4;

  float mA = -1e30f, lsA = 0.f, mB = -1e30f, lsB = 0.f;
  f32x4 oaccA[16] = {}, oaccB[16] = {};
  int kc = 0, kn2 = 2;

  for (int kt = 0; kt < 32; ++kt) {
    const ushort* kl = kbuf + kc * 8192;
    const ushort* vl = vbuf + (kt & 1) * 8192;

    __builtin_amdgcn_s_setprio(1);
    f32x4 sA[2] = {}, sB[2] = {};
#pragma unroll
    for (int kk = 0; kk < 8; ++kk) {
#pragma unroll
      for (int n = 0; n < 2; ++n) {
        bf16x8 kv = *(const bf16x8*)&kl[(n * 16 + lr) * 256 + ((kk * 32 + lg * 8) ^ (lr << 4))];
        sA[n] = __builtin_amdgcn_mfma_f32_16x16x32_bf16(kv, qfA[kk], sA[n], 0, 0, 0);
        sB[n] = __builtin_amdgcn_mfma_f32_16x16x32_bf16(kv, qfB[kk], sB[n], 0, 0, 0);
      }
    }
    __builtin_amdgcn_s_setprio(0);

    if (kt + 1 < 32) stageV(kt + 1, vbuf + ((kt + 1) & 1) * 8192);
    if (kt + 2 < 32) stageK(kt + 2, kbuf + kn2 * 8192);

    float tmA = fmaxf(fmaxf(fmaxf(sA[0][0], sA[0][1]), fmaxf(sA[0][2], sA[0][3])),
                      fmaxf(fmaxf(sA[1][0], sA[1][1]), fmaxf(sA[1][2], sA[1][3])));
    tmA = fmaxf(tmA, __shfl_xor(tmA, 16));
    tmA = fmaxf(tmA, __shfl_xor(tmA, 32));
    float tmB = fmaxf(fmaxf(fmaxf(sB[0][0], sB[0][1]), fmaxf(sB[0][2], sB[0][3])),
                      fmaxf(fmaxf(sB[1][0], sB[1][1]), fmaxf(sB[1][2], sB[1][3])));
    tmB = fmaxf(tmB, __shfl_xor(tmB, 16));
    tmB = fmaxf(tmB, __shfl_xor(tmB, 32));

    if (__any((tmA > mA + 11.5f) || (tmB > mB + 11.5f))) { // defer-max
      {
        float mn = fmaxf(mA, tmA);
        float al = fexp2(mA - mn);
        mA = mn; lsA *= al;
        float ar[4];
#pragma unroll
        for (int r2 = 0; r2 < 4; ++r2) ar[r2] = __shfl(al, lg * 4 + r2);
#pragma unroll
        for (int nf = 0; nf < 16; ++nf)
#pragma unroll
          for (int r2 = 0; r2 < 4; ++r2) oaccA[nf][r2] *= ar[r2];
      }
      {
        float mn = fmaxf(mB, tmB);
        float al = fexp2(mB - mn);
        mB = mn; lsB *= al;
        float ar[4];
#pragma unroll
        for (int r2 = 0; r2 < 4; ++r2) ar[r2] = __shfl(al, lg * 4 + r2);
#pragma unroll
        for (int nf = 0; nf < 16; ++nf)
#pragma unroll
          for (int r2 = 0; r2 < 4; ++r2) oaccB[nf][r2] *= ar[r2];
      }
    }

    uint pwA[2][2], pwB[2][2];
#pragma unroll
    for (int n = 0; n < 2; ++n) {
      float a0 = fexp2(sA[n][0] - mA), a1 = fexp2(sA[n][1] - mA);
      float a2 = fexp2(sA[n][2] - mA), a3 = fexp2(sA[n][3] - mA);
      lsA += (a0 + a1) + (a2 + a3);
      asm("v_cvt_pk_bf16_f32 %0, %1, %2" : "=v"(pwA[n][0]) : "v"(a0), "v"(a1));
      asm("v_cvt_pk_bf16_f32 %0, %1, %2" : "=v"(pwA[n][1]) : "v"(a2), "v"(a3));
      float b0 = fexp2(sB[n][0] - mB), b1 = fexp2(sB[n][1] - mB);
      float b2 = fexp2(sB[n][2] - mB), b3 = fexp2(sB[n][3] - mB);
      lsB += (b0 + b1) + (b2 + b3);
      asm("v_cvt_pk_bf16_f32 %0, %1, %2" : "=v"(pwB[n][0]) : "v"(b0), "v"(b1));
      asm("v_cvt_pk_bf16_f32 %0, %1, %2" : "=v"(pwB[n][1]) : "v"(b2), "v"(b3));
    }

    __builtin_amdgcn_s_setprio(1);
#pragma unroll
    for (int n = 0; n < 2; ++n) {
      uint2 ua; ua.x = pwA[n][0]; ua.y = pwA[n][1];
      s16x4 paA = __builtin_bit_cast(s16x4, ua);
      uint2 ub; ub.x = pwB[n][0]; ub.y = pwB[n][1];
      s16x4 paB = __builtin_bit_cast(s16x4, ub);
      const int vbase = n ? vbase1 : vbase0;
#pragma unroll
      for (int nf = 0; nf < 16; ++nf) {
        s16x4 vv = *(const s16x4*)&vl[nf * 512 + vbase];
        mfma16(oaccA[nf], paA, vv);
        mfma16(oaccB[nf], paB, vv);
      }
    }
    __builtin_amdgcn_s_setprio(0);

    if (kt < 31) {
      if (kt < 30) asm volatile("s_waitcnt vmcnt(4)" ::: "memory");
      else         asm volatile("s_waitcnt vmcnt(0)" ::: "memory");
      __builtin_amdgcn_s_barrier();
    }
    kc = (kc == 2) ? 0 : kc + 1;
    kn2 = (kn2 == 2) ? 0 : kn2 + 1;
  }

  // cross-lg row-sum reduce (each lane then holds row stats for q row wg*32+lr / +16)
  float ra = lsA; ra += __shfl_xor(ra, 16); ra += __shfl_xor(ra, 32);
  float rb = lsB; rb += __shfl_xor(rb, 16); rb += __shfl_xor(rb, 32);

  __syncthreads(); // all loop LDS reads complete before repurposing buffers

  ushort* po = lds[0];               // [128 q][256 d] bf16 partial from group 1 (64 KB)
  float* mlm = (float*)&lds[1][0];   // [128] m
  float* mll = mlm + 128;            // [128] l

  if (g == 1) {
    if (lg == 0) {
      mlm[wg * 32 + lr] = mA;       mll[wg * 32 + lr] = ra;
      mlm[wg * 32 + 16 + lr] = mB;  mll[wg * 32 + 16 + lr] = rb;
    }
#pragma unroll
    for (int nf = 0; nf < 16; ++nf)
#pragma unroll
      for (int r2 = 0; r2 < 4; ++r2) {
        int ql = wg * 32 + lg * 4 + r2;
        po[ql * 256 + nf * 16 + lr] = f2bf(oaccA[nf][r2]);
        po[(ql + 16) * 256 + nf * 16 + lr] = f2bf(oaccB[nf][r2]);
      }
  }
  __syncthreads();
  if (g == 0) {
    float mpA = mlm[wg * 32 + lr],      lpA = mll[wg * 32 + lr];
    float mpB = mlm[wg * 32 + 16 + lr], lpB = mll[wg * 32 + 16 + lr];
    float msA = fmaxf(mA, mpA);
    float fa = fexp2(mA - msA), fb = fexp2(mpA - msA);
    float lmA = ra * fa + lpA * fb;
    float msB = fmaxf(mB, mpB);
    float fa2 = fexp2(mB - msB), fb2 = fexp2(mpB - msB);
    float lmB = rb * fa2 + lpB * fb2;
    if (lg == 0) {
      float2* ml2 = (float2*)ml;
      int qp = qt * 128 + wg * 32 + lr;
      float2 va; va.x = msA; va.y = lmA;
      ml2[((size_t)(kh * 4 + b)) * 4096 + qp] = va;
      float2 vc; vc.x = msB; vc.y = lmB;
      ml2[((size_t)(kh * 4 + b)) * 4096 + qp + 16] = vc;
    }
    float far[4], fbr[4], fa2r[4], fb2r[4];
#pragma unroll
    for (int r2 = 0; r2 < 4; ++r2) {
      far[r2] = __shfl(fa, lg * 4 + r2);   fbr[r2] = __shfl(fb, lg * 4 + r2);
      fa2r[r2] = __shfl(fa2, lg * 4 + r2); fb2r[r2] = __shfl(fb2, lg * 4 + r2);
    }
    ushort* Ob = (kh ? op1 : op0) + (size_t)b * 4096 * 256;
#pragma unroll
    for (int nf = 0; nf < 16; ++nf)
#pragma unroll
      for (int r2 = 0; r2 < 4; ++r2) {
        int ql = wg * 32 + lg * 4 + r2;
        float v1 = oaccA[nf][r2] * far[r2] + bflo((uint)po[ql * 256 + nf * 16 + lr]) * fbr[r2];
        Ob[(size_t)(qt * 128 + ql) * 256 + nf * 16 + lr] = f2bf(v1);
        float v2 = oaccB[nf][r2] * fa2r[r2] + bflo((uint)po[(ql + 16) * 256 + nf * 16 + lr]) * fb2r[r2];
        Ob[(size_t)(qt * 128 + ql + 16) * 256 + nf * 16 + lr] = f2bf(v2);
      }
  }
}

extern "C" void kernel_launch(void* const* d_in, const int* in_sizes, int n_in,
                              void* d_out, int out_size, void* d_ws, size_t ws_size,
                              hipStream_t stream) {
  const float* x1 = (const float*)d_in[0];
  const float* x2 = (const float*)d_in[1];
  const float* w1 = (const float*)d_in[2];
  const float* b1 = (const float*)d_in[3];
  const float* w2 = (const float*)d_in[4];
  const float* b2 = (const float*)d_in[5];
  const float* gn_w = (const float*)d_in[6];
  const float* gn_b = (const float*)d_in[7];
  const float* wqkv = (const float*)d_in[8];
  const float* wout = (const float*)d_in[9];
  const float* bout = (const float*)d_in[10];
  const float* wsk = (const float*)d_in[11];
  const float* bsk = (const float*)d_in[12];
  float* out = (float*)d_out;

  const size_t NB = (size_t)4 * 4096 * 256;
  ushort* x1t = (ushort*)d_ws;      // later reused as q1t
  ushort* x2t = x1t + NB;           // later reused as k2t
  ushort* y1t = x2t + NB;           // persists (skip input)
  ushort* y2t = y1t + NB;           // GN'd in place -> g2t; later reused as O-partial kh=0
  ushort* g1t = y2t + NB;           // later reused as O-partial kh=1
  ushort* v2  = g1t + NB;
  ushort* w1b = v2 + NB;
  ushort* w2b = w1b + 65536;
  ushort* wqb = w2b + 65536;
  ushort* wkvb = wqb + 65536;       // 131072
  ushort* woutb = wkvb + 131072;
  ushort* wskb = woutb + 65536;
  float* mlbuf = (float*)(wskb + 65536); // 2*4*4096 float2

  cast_transpose<<<dim3(128, 8, 8), dim3(32, 8), 0, stream>>>(x1, x2, x1t, x2t);
  cast_weights<<<1792, 256, 0, stream>>>(w1, w2, wqkv, wout, wsk,
                                         w1b, w2b, wqb, wkvb, woutb, wskb);
  conv_pair<<<dim3(2, 64, 8), 256, 0, stream>>>(x1t, x2t, w1b, w2b, b1, b2, y1t, y2t);
  groupnorm<<<dim3(32, 4, 2), 256, 0, stream>>>(y1t, g1t, y2t, gn_w, gn_b);
  gemm_qkv<<<dim3(6, 64, 4), 256, 0, stream>>>(g1t, y2t, wqb, wkvb, x1t, x2t, v2);
  attn<<<256, 512, 0, stream>>>(x1t, x2t, v2, y2t, g1t, mlbuf);
  gemm_final<<<dim3(2, 64, 4), 256, 0, stream>>>(y2t, g1t, mlbuf, y1t, woutb, wskb, bout, bsk, out);
}

// Round 12
// 178.260 us; speedup vs baseline: 1.4701x; 1.2707x over previous
//
#include <hip/hip_runtime.h>

typedef unsigned int uint;
typedef unsigned short ushort;
typedef __bf16 bf16x8 __attribute__((ext_vector_type(8)));
typedef short s16x4 __attribute__((ext_vector_type(4)));
typedef float f32x4 __attribute__((ext_vector_type(4)));

__device__ __forceinline__ ushort f2bf(float f) {
  union { float f; uint u; } c; c.f = f;
  uint u = c.u + 0x7fffu + ((c.u >> 16) & 1u);
  return (ushort)(u >> 16);
}
__device__ __forceinline__ float bflo(uint u) { union { uint u; float f; } c; c.u = u << 16; return c.f; }
__device__ __forceinline__ float bfhi(uint u) { union { uint u; float f; } c; c.u = u & 0xffff0000u; return c.f; }

__device__ __forceinline__ void gload16(const void* g, void* l) {
  __builtin_amdgcn_global_load_lds((const __attribute__((address_space(1))) void*)g,
                                   (__attribute__((address_space(3))) void*)l, 16, 0, 0);
}
__device__ __forceinline__ void mfma16(f32x4& acc, s16x4 a, s16x4 b) {
  asm("v_mfma_f32_16x16x16_bf16 %0, %1, %2, %0" : "+v"(acc) : "v"(a), "v"(b));
}
__device__ __forceinline__ float fexp2(float x) {
  float y; asm("v_exp_f32 %0, %1" : "=v"(y) : "v"(x)); return y;
}

// ---------------- cast + transpose: x [B][C][4096] f32 -> xt [B][4096][C] bf16 (both tensors) ----------------
__global__ void cast_transpose(const float* __restrict__ x1, const float* __restrict__ x2,
                               ushort* __restrict__ x1t, ushort* __restrict__ x2t) {
  __shared__ float t[32][33];
  const int z = blockIdx.z, b = z & 3, tn = z >> 2;
  const float* x = tn ? x2 : x1;
  ushort* xt = tn ? x2t : x1t;
  const int pc = blockIdx.x, cc = blockIdx.y;
  const int tx = threadIdx.x, ty = threadIdx.y; // 32 x 8
  const float* xb = x + ((size_t)b * 256 + cc * 32) * 4096 + pc * 32;
#pragma unroll
  for (int i = 0; i < 4; ++i)
    t[ty * 4 + i][tx] = xb[(size_t)(ty * 4 + i) * 4096 + tx];
  __syncthreads();
  ushort* xtb = xt + ((size_t)b * 4096 + pc * 32) * 256 + cc * 32;
#pragma unroll
  for (int i = 0; i < 4; ++i)
    xtb[(size_t)(ty * 4 + i) * 256 + tx] = f2bf(t[tx][ty * 4 + i]);
}

// ---------------- all weights -> bf16, one kernel. Q weights get 1/sqrt(C)*log2(e) folded in. ----------------
__global__ void cast_weights(const float* __restrict__ w1, const float* __restrict__ w2,
                             const float* __restrict__ wqkv, const float* __restrict__ wout,
                             const float* __restrict__ wsk,
                             ushort* __restrict__ w1b, ushort* __restrict__ w2b,
                             ushort* __restrict__ wqb, ushort* __restrict__ wkvb,
                             ushort* __restrict__ woutb, ushort* __restrict__ wskb) {
  const int i = blockIdx.x * 256 + threadIdx.x;
  const float QS = 0.0625f * 1.44269504088896f;
  if (i < 65536) w1b[i] = f2bf(w1[i]);
  else if (i < 131072) w2b[i - 65536] = f2bf(w2[i - 65536]);
  else if (i < 196608) wqb[i - 131072] = f2bf(wqkv[i - 131072] * QS);
  else if (i < 327680) wkvb[i - 196608] = f2bf(wqkv[i - 131072]);
  else if (i < 393216) woutb[i - 327680] = f2bf(wout[i - 327680]);
  else wskb[i - 393216] = f2bf(wsk[i - 393216]);
}

// ---------------- GN finalize: per-channel scale/shift table from per-block partials ----------------
// pbuf [2 t][4 b][32 g][64 yblk][2] f32 (written non-atomically by conv_pair). tab [2][4][256] float2.
__global__ void gn_finalize(const float* __restrict__ pbuf, const float* __restrict__ gn_w,
                            const float* __restrict__ gn_b, float* __restrict__ tab) {
  const int idx = blockIdx.x * 256 + threadIdx.x; // 0..2047
  const int t = idx >> 10, b = (idx >> 8) & 3, c = idx & 255, g = c >> 3;
  const float* p = pbuf + (size_t)(((t * 4 + b) * 32 + g) * 64) * 2;
  float s = 0.f, ss = 0.f;
#pragma unroll 8
  for (int y = 0; y < 64; ++y) { s += p[y * 2]; ss += p[y * 2 + 1]; }
  float mu = s * (1.f / 32768.f);
  float var = ss * (1.f / 32768.f) - mu * mu;
  float rstd = rsqrtf(var + 1e-5f);
  float scale = gn_w[c] * rstd;
  float shift = gn_b[c] - mu * scale;
  float2 v; v.x = scale; v.y = shift;
  ((float2*)tab)[(t * 4 + b) * 256 + c] = v;
}

// ---------------- shared GEMM pieces: 64x128 tile, K-step 64, double-buffered LDS ----------------
__device__ __forceinline__ void g_stage_a64(const ushort* __restrict__ A,
                                            int m0, int ko, ushort* al, int w, int l) {
#pragma unroll
  for (int j = 0; j < 2; ++j) {
    int cb = (j * 4 + w) * 64;
    int chunk = cb + l;                 // 0..511
    int row = chunk >> 3, sl = chunk & 7;
    int col = (sl * 8) ^ ((row & 7) << 3);
    gload16(A + (size_t)(m0 + row) * 256 + ko + col, al + chunk * 8);
  }
}

__device__ __forceinline__ void g_stage_b64(const ushort* __restrict__ W,
                                            int n0, int ko, ushort* bl, int w, int l) {
#pragma unroll
  for (int j = 0; j < 4; ++j) {
    int cb = (j * 4 + w) * 64;
    int chunk = cb + l;                 // 0..1023
    int row = chunk >> 3, sl = chunk & 7;
    int col = (sl * 8) ^ ((row & 7) << 3);
    gload16(W + (size_t)(n0 + row) * 256 + ko + col, bl + chunk * 8);
  }
}

__device__ __forceinline__ void g_compute64(const ushort* al, const ushort* bl,
                                            int w, int lr, int lg, f32x4 acc[4][2]) {
#pragma unroll
  for (int kk = 0; kk < 2; ++kk) {
    bf16x8 af[4], bfr[2];
#pragma unroll
    for (int m = 0; m < 4; ++m)
      af[m] = *(const bf16x8*)&al[(m * 16 + lr) * 64 + ((kk * 32 + lg * 8) ^ ((lr & 7) << 3))];
#pragma unroll
    for (int n = 0; n < 2; ++n)
      bfr[n] = *(const bf16x8*)&bl[(w * 32 + n * 16 + lr) * 64 + ((kk * 32 + lg * 8) ^ ((lr & 7) << 3))];
#pragma unroll
    for (int m = 0; m < 4; ++m)
#pragma unroll
      for (int n = 0; n < 2; ++n)
        acc[m][n] = __builtin_amdgcn_mfma_f32_16x16x32_bf16(af[m], bfr[n], acc[m][n], 0, 0, 0);
  }
}

// ---------------- conv1 + conv2 fused + GN partial stats: z = t*4 + b ----------------
__launch_bounds__(256)
__global__ void conv_pair(const ushort* __restrict__ x1t, const ushort* __restrict__ x2t,
                          const ushort* __restrict__ w1b, const ushort* __restrict__ w2b,
                          const float* __restrict__ b1, const float* __restrict__ b2,
                          ushort* __restrict__ y1t, ushort* __restrict__ y2t,
                          float* __restrict__ pbuf) {
  __shared__ ushort al[2][4096];
  __shared__ ushort bl[2][8192];
  const int z = blockIdx.z, b = z & 3, t = z >> 2;
  const ushort* A = (t ? x2t : x1t) + (size_t)b * 4096 * 256;
  const ushort* W = t ? w2b : w1b;
  const float* bias = t ? b2 : b1;
  ushort* out = t ? y2t : y1t;
  const int m0 = blockIdx.y * 64, n0 = blockIdx.x * 128;
  const int tid = threadIdx.x, w = tid >> 6, l = tid & 63;
  const int lr = l & 15, lg = l >> 4;
  f32x4 acc[4][2] = {};
  g_stage_a64(A, m0, 0, al[0], w, l);
  g_stage_b64(W, n0, 0, bl[0], w, l);
  __syncthreads();
  for (int s = 0; s < 4; ++s) {
    int cur = s & 1;
    if (s + 1 < 4) {
      g_stage_a64(A, m0, (s + 1) * 64, al[cur ^ 1], w, l);
      g_stage_b64(W, n0, (s + 1) * 64, bl[cur ^ 1], w, l);
    }
    g_compute64(al[cur], bl[cur], w, lr, lg, acc);
    __syncthreads();
  }
  float sg[2] = { 0.f, 0.f }, sq[2] = { 0.f, 0.f };
#pragma unroll
  for (int n = 0; n < 2; ++n) {
    int o = n0 + w * 32 + n * 16 + lr;
    float bv = bias[o];
#pragma unroll
    for (int m = 0; m < 4; ++m) {
      int p0 = m0 + m * 16 + lg * 4;
#pragma unroll
      for (int r = 0; r < 4; ++r) {
        float val = acc[m][n][r] + bv;
        out[((size_t)b * 4096 + p0 + r) * 256 + o] = f2bf(val);
        sg[n] += val; sq[n] += val * val;
      }
    }
  }
  // reduce per group (8 channels = 8 lr-lanes) over all lanes except bit3; lanes 0 and 8 store
#pragma unroll
  for (int n = 0; n < 2; ++n) {
    float s1 = sg[n], s2 = sq[n];
    s1 += __shfl_xor(s1, 16); s2 += __shfl_xor(s2, 16);
    s1 += __shfl_xor(s1, 32); s2 += __shfl_xor(s2, 32);
    s1 += __shfl_xor(s1, 1);  s2 += __shfl_xor(s2, 1);
    s1 += __shfl_xor(s1, 2);  s2 += __shfl_xor(s2, 2);
    s1 += __shfl_xor(s1, 4);  s2 += __shfl_xor(s2, 4);
    if (l == 0 || l == 8) {
      int go = (n0 + w * 32 + n * 16 + (l & 8)) >> 3;
      float* dst = pbuf + (size_t)((((t * 4 + b) * 32 + go) * 64) + blockIdx.y) * 2;
      dst[0] = s1; dst[1] = s2;
    }
  }
}

// ---------------- q-proj + kv-proj fused, GN applied inline during reg-staged A (T14 split) -------------
// x<2 -> q1 = GN(y1)@wq^T (from y1t), x>=2 -> [k2|v2] = GN(y2)@wkv^T (from y2t).
__launch_bounds__(256)
__global__ void gemm_qkv(const ushort* __restrict__ y1t, const ushort* __restrict__ y2t,
                         const ushort* __restrict__ wqb, const ushort* __restrict__ wkvb,
                         const float* __restrict__ tab,
                         ushort* __restrict__ q1t, ushort* __restrict__ k2t, ushort* __restrict__ v2) {
  __shared__ ushort al[2][4096];
  __shared__ ushort bl[2][8192];
  const int b = blockIdx.z, x = blockIdx.x;
  const bool isq = x < 2;
  const ushort* A = (isq ? y1t : y2t) + (size_t)b * 4096 * 256;
  const ushort* W = isq ? wqb : wkvb;
  const float* tabp = tab + (size_t)((isq ? 0 : 1) * 4 + b) * 512; // 256 ch x {scale,shift}
  const int n0 = isq ? x * 128 : (x - 2) * 128;
  const int m0 = blockIdx.y * 64;
  const int tid = threadIdx.x, w = tid >> 6, l = tid & 63;
  const int lr = l & 15, lg = l >> 4;

  int rowj[2], colj[2], ldsj[2];
#pragma unroll
  for (int j = 0; j < 2; ++j) {
    int chunk = (j * 4 + w) * 64 + l;
    int row = chunk >> 3, sl = chunk & 7;
    rowj[j] = row; colj[j] = sl * 8;
    ldsj[j] = row * 64 + ((sl * 8) ^ ((row & 7) << 3));
  }

  auto loadA = [&](int ko, uint4* av, float4 tv[2][4]) {
#pragma unroll
    for (int j = 0; j < 2; ++j) {
      av[j] = *(const uint4*)(A + (size_t)(m0 + rowj[j]) * 256 + ko + colj[j]);
      const float4* tp = (const float4*)(tabp + 2 * (ko + colj[j]));
      tv[j][0] = tp[0]; tv[j][1] = tp[1]; tv[j][2] = tp[2]; tv[j][3] = tp[3];
    }
  };
  auto writeA = [&](const uint4* av, const float4 tv[2][4], ushort* al_) {
#pragma unroll
    for (int j = 0; j < 2; ++j) {
      uint rr[4] = { av[j].x, av[j].y, av[j].z, av[j].w };
      ushort o[8];
#pragma unroll
      for (int q = 0; q < 4; ++q) {
        o[q * 2]     = f2bf(bflo(rr[q]) * tv[j][q].x + tv[j][q].y);
        o[q * 2 + 1] = f2bf(bfhi(rr[q]) * tv[j][q].z + tv[j][q].w);
      }
      uint4 wv;
      wv.x = (uint)o[0] | ((uint)o[1] << 16); wv.y = (uint)o[2] | ((uint)o[3] << 16);
      wv.z = (uint)o[4] | ((uint)o[5] << 16); wv.w = (uint)o[6] | ((uint)o[7] << 16);
      *(uint4*)&al_[ldsj[j]] = wv;
    }
  };

  f32x4 acc[4][2] = {};
  {
    uint4 av[2]; float4 tv[2][4];
    loadA(0, av, tv);
    g_stage_b64(W, n0, 0, bl[0], w, l);
    writeA(av, tv, al[0]);
  }
  __syncthreads();
  for (int s = 0; s < 4; ++s) {
    int cur = s & 1;
    uint4 av[2]; float4 tv[2][4];
    if (s + 1 < 4) {
      loadA((s + 1) * 64, av, tv);                 // issue global loads early
      g_stage_b64(W, n0, (s + 1) * 64, bl[cur ^ 1], w, l);
    }
    g_compute64(al[cur], bl[cur], w, lr, lg, acc); // loads' latency hides here
    if (s + 1 < 4) writeA(av, tv, al[cur ^ 1]);    // normalized ds_write after compute
    __syncthreads();
  }
#pragma unroll
  for (int n = 0; n < 2; ++n) {
    int o = n0 + w * 32 + n * 16 + lr;
#pragma unroll
    for (int m = 0; m < 4; ++m) {
      int p0 = m0 + m * 16 + lg * 4;
#pragma unroll
      for (int r = 0; r < 4; ++r) {
        float val = acc[m][n][r];
        int p = p0 + r;
        if (isq) q1t[((size_t)b * 4096 + p) * 256 + o] = f2bf(val);
        else if (o < 256) k2t[((size_t)b * 4096 + p) * 256 + o] = f2bf(val);
        else v2[((size_t)b * 256 + (o - 256)) * 4096 + p] = f2bf(val);
      }
    }
  }
}

// ---------------- final: out = merge(op0,op1)@wout^T + bout + y1@wsk^T + bsk, f32 channel-major -------------
__launch_bounds__(256)
__global__ void gemm_final(const ushort* __restrict__ op0, const ushort* __restrict__ op1,
                           const float* __restrict__ ml, const ushort* __restrict__ y1t,
                           const ushort* __restrict__ woutb, const ushort* __restrict__ wskb,
                           const float* __restrict__ bout, const float* __restrict__ bsk,
                           float* __restrict__ out) {
  __shared__ ushort smem[24576]; // al0 4096, al1 4096, bl0 8192, bl1 8192 (ushorts) = 48KB
  ushort* al0 = smem;            ushort* al1 = smem + 4096;
  ushort* bl0 = smem + 8192;     ushort* bl1 = smem + 16384;
  const int b = blockIdx.z;
  const int m0 = blockIdx.y * 64, n0 = blockIdx.x * 128;
  const int tid = threadIdx.x, w = tid >> 6, l = tid & 63;
  const int lr = l & 15, lg = l >> 4;
  const float2* ml2 = (const float2*)ml;
  const ushort* A1 = y1t + (size_t)b * 4096 * 256;

  int rowj[2], colj[2], ldsj[2];
  float w0j[2], w1j[2];
#pragma unroll
  for (int j = 0; j < 2; ++j) {
    int chunk = (j * 4 + w) * 64 + l;
    int row = chunk >> 3, sl = chunk & 7;
    rowj[j] = row; colj[j] = sl * 8;
    ldsj[j] = row * 64 + ((sl * 8) ^ ((row & 7) << 3));
    float2 a = ml2[(size_t)b * 4096 + m0 + row];
    float2 c = ml2[(size_t)(4 + b) * 4096 + m0 + row];
    float m = fmaxf(a.x, c.x);
    float e0 = fexp2(a.x - m), e1 = fexp2(c.x - m);
    float inv = 1.f / (a.y * e0 + c.y * e1);
    w0j[j] = e0 * inv; w1j[j] = e1 * inv;
  }

  auto stageA_merge = [&](int ko, ushort* al) {
    uint4 r0[2], r1[2];
#pragma unroll
    for (int j = 0; j < 2; ++j) {
      size_t off = ((size_t)b * 4096 + m0 + rowj[j]) * 256 + ko + colj[j];
      r0[j] = *(const uint4*)(op0 + off);
      r1[j] = *(const uint4*)(op1 + off);
    }
#pragma unroll
    for (int j = 0; j < 2; ++j) {
      uint rr[4] = { r0[j].x, r0[j].y, r0[j].z, r0[j].w };
      uint ss[4] = { r1[j].x, r1[j].y, r1[j].z, r1[j].w };
      ushort o[8];
#pragma unroll
      for (int q = 0; q < 4; ++q) {
        o[q * 2]     = f2bf(bflo(rr[q]) * w0j[j] + bflo(ss[q]) * w1j[j]);
        o[q * 2 + 1] = f2bf(bfhi(rr[q]) * w0j[j] + bfhi(ss[q]) * w1j[j]);
      }
      uint4 wv;
      wv.x = (uint)o[0] | ((uint)o[1] << 16); wv.y = (uint)o[2] | ((uint)o[3] << 16);
      wv.z = (uint)o[4] | ((uint)o[5] << 16); wv.w = (uint)o[6] | ((uint)o[7] << 16);
      *(uint4*)&al[ldsj[j]] = wv;
    }
  };

  f32x4 acc[4][2] = {};
  stageA_merge(0, al0);
  g_stage_b64(woutb, n0, 0, bl0, w, l);
  __syncthreads();
  for (int s = 0; s < 8; ++s) {
    int cur = s & 1;
    if (s + 1 < 8) {
      int ko = ((s + 1) & 3) * 64;
      ushort* an = cur ? al0 : al1;
      ushort* bn = cur ? bl0 : bl1;
      if (s + 1 < 4) stageA_merge(ko, an);
      else g_stage_a64(A1, m0, ko, an, w, l);
      g_stage_b64((s + 1 >= 4) ? wskb : woutb, n0, ko, bn, w, l);
    }
    g_compute64(cur ? al1 : al0, cur ? bl1 : bl0, w, lr, lg, acc);
    __syncthreads();
  }
  float4* cl = (float4*)smem; // [128 o][16 f4] = 32KB
#pragma unroll
  for (int n = 0; n < 2; ++n) {
    int o = w * 32 + n * 16 + lr;
    float bv = bout[n0 + o] + bsk[n0 + o];
#pragma unroll
    for (int m = 0; m < 4; ++m) {
      int pf4 = m * 4 + lg;
      f32x4 v = acc[m][n];
      float4 vv; vv.x = v[0] + bv; vv.y = v[1] + bv; vv.z = v[2] + bv; vv.w = v[3] + bv;
      cl[o * 16 + (pf4 ^ (o & 15))] = vv;
    }
  }
  __syncthreads();
  float4* og = (float4*)(out + ((size_t)b * 256 + n0) * 4096 + m0);
#pragma unroll
  for (int i = 0; i < 8; ++i) {
    int o = i * 16 + (tid >> 4);
    int f4 = tid & 15;
    og[(size_t)o * 1024 + f4] = cl[o * 16 + (f4 ^ (o & 15))];
  }
}

// ---------------- flash attention: 512-thread blocks, q-width 32/wave, in-block k-pair merge ----------------
// (unchanged from round 10: 115.5 us, MfmaUtil 36.7%, 2 waves/SIMD)
__launch_bounds__(512, 2)
__global__ void attn(const ushort* __restrict__ Q, const ushort* __restrict__ K,
                     const ushort* __restrict__ V, ushort* __restrict__ op0,
                     ushort* __restrict__ op1, float* __restrict__ ml) {
  __shared__ ushort lds[2][40960]; // per group: K 3x8192 @ 0, V 2x8192 @ 24576 (ushorts); 160 KB total
  const int bid = blockIdx.x;
  const int xcd = bid & 7, r = bid >> 3;
  const int b = xcd >> 1;
  const int kh = r & 1;
  const int qt = (xcd & 1) * 16 + (r >> 1);   // 0..31, QBLK=128
  const int tid = threadIdx.x;
  const int w = tid >> 6, l = tid & 63;
  const int g = w >> 2, wg = w & 3;
  const int lr = l & 15, lg = l >> 4;

  const ushort* Qb = Q + (size_t)b * 4096 * 256;
  const ushort* Kb = K + (size_t)b * 4096 * 256 + (size_t)(kh * 2048 + g * 1024) * 256;
  const ushort* Vb = V + (size_t)b * 256 * 4096 + kh * 2048 + g * 1024;

  ushort* kbuf = lds[g];
  ushort* vbuf = lds[g] + 24576;

  int kOff[4], vOff[4];
#pragma unroll
  for (int j = 0; j < 4; ++j) {
    int c = (j * 4 + wg) * 64 + l;
    int krow = c >> 5, ksl = c & 31;
    kOff[j] = krow * 256 + ((ksl * 8) ^ ((krow & 15) << 4));
    int R = c >> 2, CH = c & 3;
    int vd = R ^ ((R >> 1) & 1);
    int gch = CH ^ ((R >> 1) & 3);
    vOff[j] = vd * 4096 + gch * 8;
  }
  auto stageK = [&](int kt, ushort* dst) {
#pragma unroll
    for (int j = 0; j < 4; ++j)
      gload16(Kb + (size_t)kt * 8192 + kOff[j], dst + (j * 4 + wg) * 512);
  };
  auto stageV = [&](int kt, ushort* dst) {
#pragma unroll
    for (int j = 0; j < 4; ++j)
      gload16(Vb + (size_t)kt * 32 + vOff[j], dst + (j * 4 + wg) * 512);
  };

  bf16x8 qfA[8], qfB[8];
  {
    const ushort* qa = Qb + (size_t)(qt * 128 + wg * 32 + lr) * 256 + lg * 8;
    const ushort* qc = qa + 16 * 256;
#pragma unroll
    for (int kk = 0; kk < 8; ++kk) {
      qfA[kk] = *(const bf16x8*)(qa + kk * 32);
      qfB[kk] = *(const bf16x8*)(qc + kk * 32);
    }
  }

  stageK(0, kbuf);
  stageV(0, vbuf);
  stageK(1, kbuf + 8192);
  asm volatile("s_waitcnt vmcnt(4)" ::: "memory");
  __builtin_amdgcn_s_barrier();

  const int lrp = lr ^ ((lr >> 1) & 1);
  const int vsw = (lr >> 1) & 3;
  const int vbase0 = lrp * 32 + (((lg >> 1)) ^ vsw) * 8 + (lg & 1) * 4;
  const int vbase1 = lrp * 32 + ((2 + (lg >> 1)) ^ vsw) * 8 + (lg & 1) * 4;

  float mA = -1e30f, lsA = 0.f, mB = -1e30f, lsB = 0.f;
  f32x4 oaccA[16] = {}, oaccB[16] = {};
  int kc = 0, kn2 = 2;

  for (int kt = 0; kt < 32; ++kt) {
    const ushort* kl = kbuf + kc * 8192;
    const ushort* vl = vbuf + (kt & 1) * 8192;

    __builtin_amdgcn_s_setprio(1);
    f32x4 sA[2] = {}, sB[2] = {};
#pragma unroll
    for (int kk = 0; kk < 8; ++kk) {
#pragma unroll
      for (int n = 0; n < 2; ++n) {
        bf16x8 kv = *(const bf16x8*)&kl[(n * 16 + lr) * 256 + ((kk * 32 + lg * 8) ^ (lr << 4))];
        sA[n] = __builtin_amdgcn_mfma_f32_16x16x32_bf16(kv, qfA[kk], sA[n], 0, 0, 0);
        sB[n] = __builtin_amdgcn_mfma_f32_16x16x32_bf16(kv, qfB[kk], sB[n], 0, 0, 0);
      }
    }
    __builtin_amdgcn_s_setprio(0);

    if (kt + 1 < 32) stageV(kt + 1, vbuf + ((kt + 1) & 1) * 8192);
    if (kt + 2 < 32) stageK(kt + 2, kbuf + kn2 * 8192);

    float tmA = fmaxf(fmaxf(fmaxf(sA[0][0], sA[0][1]), fmaxf(sA[0][2], sA[0][3])),
                      fmaxf(fmaxf(sA[1][0], sA[1][1]), fmaxf(sA[1][2], sA[1][3])));
    tmA = fmaxf(tmA, __shfl_xor(tmA, 16));
    tmA = fmaxf(tmA, __shfl_xor(tmA, 32));
    float tmB = fmaxf(fmaxf(fmaxf(sB[0][0], sB[0][1]), fmaxf(sB[0][2], sB[0][3])),
                      fmaxf(fmaxf(sB[1][0], sB[1][1]), fmaxf(sB[1][2], sB[1][3])));
    tmB = fmaxf(tmB, __shfl_xor(tmB, 16));
    tmB = fmaxf(tmB, __shfl_xor(tmB, 32));

    if (__any((tmA > mA + 11.5f) || (tmB > mB + 11.5f))) { // defer-max
      {
        float mn = fmaxf(mA, tmA);
        float al = fexp2(mA - mn);
        mA = mn; lsA *= al;
        float ar[4];
#pragma unroll
        for (int r2 = 0; r2 < 4; ++r2) ar[r2] = __shfl(al, lg * 4 + r2);
#pragma unroll
        for (int nf = 0; nf < 16; ++nf)
#pragma unroll
          for (int r2 = 0; r2 < 4; ++r2) oaccA[nf][r2] *= ar[r2];
      }
      {
        float mn = fmaxf(mB, tmB);
        float al = fexp2(mB - mn);
        mB = mn; lsB *= al;
        float ar[4];
#pragma unroll
        for (int r2 = 0; r2 < 4; ++r2) ar[r2] = __shfl(al, lg * 4 + r2);
#pragma unroll
        for (int nf = 0; nf < 16; ++nf)
#pragma unroll
          for (int r2 = 0; r2 < 4; ++r2) oaccB[nf][r2] *= ar[r2];
      }
    }

    uint pwA[2][2], pwB[2][2];
#pragma unroll
    for (int n = 0; n < 2; ++n) {
      float a0 = fexp2(sA[n][0] - mA), a1 = fexp2(sA[n][1] - mA);
      float a2 = fexp2(sA[n][2] - mA), a3 = fexp2(sA[n][3] - mA);
      lsA += (a0 + a1) + (a2 + a3);
      asm("v_cvt_pk_bf16_f32 %0, %1, %2" : "=v"(pwA[n][0]) : "v"(a0), "v"(a1));
      asm("v_cvt_pk_bf16_f32 %0, %1, %2" : "=v"(pwA[n][1]) : "v"(a2), "v"(a3));
      float b0 = fexp2(sB[n][0] - mB), b1 = fexp2(sB[n][1] - mB);
      float b2 = fexp2(sB[n][2] - mB), b3 = fexp2(sB[n][3] - mB);
      lsB += (b0 + b1) + (b2 + b3);
      asm("v_cvt_pk_bf16_f32 %0, %1, %2" : "=v"(pwB[n][0]) : "v"(b0), "v"(b1));
      asm("v_cvt_pk_bf16_f32 %0, %1, %2" : "=v"(pwB[n][1]) : "v"(b2), "v"(b3));
    }

    __builtin_amdgcn_s_setprio(1);
#pragma unroll
    for (int n = 0; n < 2; ++n) {
      uint2 ua; ua.x = pwA[n][0]; ua.y = pwA[n][1];
      s16x4 paA = __builtin_bit_cast(s16x4, ua);
      uint2 ub; ub.x = pwB[n][0]; ub.y = pwB[n][1];
      s16x4 paB = __builtin_bit_cast(s16x4, ub);
      const int vbase = n ? vbase1 : vbase0;
#pragma unroll
      for (int nf = 0; nf < 16; ++nf) {
        s16x4 vv = *(const s16x4*)&vl[nf * 512 + vbase];
        mfma16(oaccA[nf], paA, vv);
        mfma16(oaccB[nf], paB, vv);
      }
    }
    __builtin_amdgcn_s_setprio(0);

    if (kt < 31) {
      if (kt < 30) asm volatile("s_waitcnt vmcnt(4)" ::: "memory");
      else         asm volatile("s_waitcnt vmcnt(0)" ::: "memory");
      __builtin_amdgcn_s_barrier();
    }
    kc = (kc == 2) ? 0 : kc + 1;
    kn2 = (kn2 == 2) ? 0 : kn2 + 1;
  }

  float ra = lsA; ra += __shfl_xor(ra, 16); ra += __shfl_xor(ra, 32);
  float rb = lsB; rb += __shfl_xor(rb, 16); rb += __shfl_xor(rb, 32);

  __syncthreads();

  ushort* po = lds[0];
  float* mlm = (float*)&lds[1][0];
  float* mll = mlm + 128;

  if (g == 1) {
    if (lg == 0) {
      mlm[wg * 32 + lr] = mA;       mll[wg * 32 + lr] = ra;
      mlm[wg * 32 + 16 + lr] = mB;  mll[wg * 32 + 16 + lr] = rb;
    }
#pragma unroll
    for (int nf = 0; nf < 16; ++nf)
#pragma unroll
      for (int r2 = 0; r2 < 4; ++r2) {
        int ql = wg * 32 + lg * 4 + r2;
        po[ql * 256 + nf * 16 + lr] = f2bf(oaccA[nf][r2]);
        po[(ql + 16) * 256 + nf * 16 + lr] = f2bf(oaccB[nf][r2]);
      }
  }
  __syncthreads();
  if (g == 0) {
    float mpA = mlm[wg * 32 + lr],      lpA = mll[wg * 32 + lr];
    float mpB = mlm[wg * 32 + 16 + lr], lpB = mll[wg * 32 + 16 + lr];
    float msA = fmaxf(mA, mpA);
    float fa = fexp2(mA - msA), fb = fexp2(mpA - msA);
    float lmA = ra * fa + lpA * fb;
    float msB = fmaxf(mB, mpB);
    float fa2 = fexp2(mB - msB), fb2 = fexp2(mpB - msB);
    float lmB = rb * fa2 + lpB * fb2;
    if (lg == 0) {
      float2* ml2 = (float2*)ml;
      int qp = qt * 128 + wg * 32 + lr;
      float2 va; va.x = msA; va.y = lmA;
      ml2[((size_t)(kh * 4 + b)) * 4096 + qp] = va;
      float2 vc; vc.x = msB; vc.y = lmB;
      ml2[((size_t)(kh * 4 + b)) * 4096 + qp + 16] = vc;
    }
    float far[4], fbr[4], fa2r[4], fb2r[4];
#pragma unroll
    for (int r2 = 0; r2 < 4; ++r2) {
      far[r2] = __shfl(fa, lg * 4 + r2);   fbr[r2] = __shfl(fb, lg * 4 + r2);
      fa2r[r2] = __shfl(fa2, lg * 4 + r2); fb2r[r2] = __shfl(fb2, lg * 4 + r2);
    }
    ushort* Ob = (kh ? op1 : op0) + (size_t)b * 4096 * 256;
#pragma unroll
    for (int nf = 0; nf < 16; ++nf)
#pragma unroll
      for (int r2 = 0; r2 < 4; ++r2) {
        int ql = wg * 32 + lg * 4 + r2;
        float v1 = oaccA[nf][r2] * far[r2] + bflo((uint)po[ql * 256 + nf * 16 + lr]) * fbr[r2];
        Ob[(size_t)(qt * 128 + ql) * 256 + nf * 16 + lr] = f2bf(v1);
        float v2 = oaccB[nf][r2] * fa2r[r2] + bflo((uint)po[(ql + 16) * 256 + nf * 16 + lr]) * fb2r[r2];
        Ob[(size_t)(qt * 128 + ql + 16) * 256 + nf * 16 + lr] = f2bf(v2);
      }
  }
}

extern "C" void kernel_launch(void* const* d_in, const int* in_sizes, int n_in,
                              void* d_out, int out_size, void* d_ws, size_t ws_size,
                              hipStream_t stream) {
  const float* x1 = (const float*)d_in[0];
  const float* x2 = (const float*)d_in[1];
  const float* w1 = (const float*)d_in[2];
  const float* b1 = (const float*)d_in[3];
  const float* w2 = (const float*)d_in[4];
  const float* b2 = (const float*)d_in[5];
  const float* gn_w = (const float*)d_in[6];
  const float* gn_b = (const float*)d_in[7];
  const float* wqkv = (const float*)d_in[8];
  const float* wout = (const float*)d_in[9];
  const float* bout = (const float*)d_in[10];
  const float* wsk = (const float*)d_in[11];
  const float* bsk = (const float*)d_in[12];
  float* out = (float*)d_out;

  const size_t NB = (size_t)4 * 4096 * 256;
  ushort* x1t = (ushort*)d_ws;      // later reused as q1t
  ushort* x2t = x1t + NB;           // later reused as k2t
  ushort* y1t = x2t + NB;           // persists (skip + q-proj input)
  ushort* y2t = y1t + NB;           // kv-proj input; later reused as O-partial kh=0
  ushort* g1t = y2t + NB;           // O-partial kh=1 (no longer a GN output)
  ushort* v2  = g1t + NB;
  ushort* w1b = v2 + NB;
  ushort* w2b = w1b + 65536;
  ushort* wqb = w2b + 65536;
  ushort* wkvb = wqb + 65536;       // 131072
  ushort* woutb = wkvb + 131072;
  ushort* wskb = woutb + 65536;
  float* mlbuf = (float*)(wskb + 65536); // 2*4*4096 float2 = 65536 floats
  float* pbuf  = mlbuf + 65536;          // 2*4*32*64*2 = 32768 floats (GN partials)
  float* tabbuf = pbuf + 32768;          // 2*4*256 float2 = 4096 floats (GN scale/shift)

  cast_transpose<<<dim3(128, 8, 8), dim3(32, 8), 0, stream>>>(x1, x2, x1t, x2t);
  cast_weights<<<1792, 256, 0, stream>>>(w1, w2, wqkv, wout, wsk,
                                         w1b, w2b, wqb, wkvb, woutb, wskb);
  conv_pair<<<dim3(2, 64, 8), 256, 0, stream>>>(x1t, x2t, w1b, w2b, b1, b2, y1t, y2t, pbuf);
  gn_finalize<<<8, 256, 0, stream>>>(pbuf, gn_w, gn_b, tabbuf);
  gemm_qkv<<<dim3(6, 64, 4), 256, 0, stream>>>(y1t, y2t, wqb, wkvb, tabbuf, x1t, x2t, v2);
  attn<<<256, 512, 0, stream>>>(x1t, x2t, v2, y2t, g1t, mlbuf);
  gemm_final<<<dim3(2, 64, 4), 256, 0, stream>>>(y2t, g1t, mlbuf, y1t, woutb, wskb, bout, bsk, out);
}